// Round 8
// baseline (1598.943 us; speedup 1.0000x reference)
//
#include <hip/hip_runtime.h>
#include <hip/hip_bf16.h>
#include <math.h>

// Problem constants
#define BATCH 4
#define CDIM 192
#define HDIM 224
#define WDIM 224
#define HWSZ (HDIM * WDIM)            // 50176
#define NWH 28                        // 224/8
#define NWIN (BATCH * NWH * NWH)      // 3136
#define TOK 64
#define MTOK (NWIN * TOK)             // 200704
#define HEADS 6
#define C3 (3 * CDIM)                 // 576
#define C4 (4 * CDIM)                 // 768
#define IMGSZ (BATCH * CDIM * HWSZ)   // 38535168
#define ATTN_SCALE 0.17677669529663687f
#define LN_EPS 1e-6f
#define PBP 200                        // pb row pitch (ushorts), 400 B, 16B-aligned

typedef __attribute__((ext_vector_type(8))) short bfrag;   // 8 bf16 (4 VGPRs)
typedef __attribute__((ext_vector_type(4))) float f32x4;

__device__ __forceinline__ float bf2f(unsigned short u) {
    union { unsigned int i; float f; } v; v.i = ((unsigned int)u) << 16; return v.f;
}
__device__ __forceinline__ unsigned short f2bf(float f) {
    union { unsigned int i; float f; } v; v.f = f;
    unsigned int r = (v.i + 0x7FFFu + ((v.i >> 16) & 1u)) >> 16;   // RNE
    return (unsigned short)r;
}
// exact-erf GELU via Abramowitz-Stegun 7.1.26 (|erf err| <= 1.5e-7)
__device__ __forceinline__ float gelu_erf(float x) {
    float z = fabsf(x) * 0.70710678118654752f;
    float t = __fdividef(1.0f, 1.0f + 0.3275911f * z);
    float poly = t * (0.254829592f + t * (-0.284496736f +
                 t * (1.421413741f + t * (-1.453152027f + t * 1.061405429f))));
    float erfv = 1.0f - poly * __expf(-z * z);
    erfv = (x < 0.f) ? -erfv : erfv;
    return 0.5f * x * (1.0f + erfv);
}
// async global->LDS, 16B per lane; LDS dest = uniform base + lane*16 (HW)
__device__ __forceinline__ void gload16(void* lds, const void* g) {
    __builtin_amdgcn_global_load_lds(
        (const __attribute__((address_space(1))) void*)g,
        (__attribute__((address_space(3))) void*)lds, 16, 0, 0);
}

// ---------------------------------------------------------------------------
// Prep: transpose+convert weights to bf16 (n-major, k-contiguous) once/launch.
// WqkvT full 576x192. W2C chunk-contiguous [hc][n(192)][kloc(64)].
// WpT/WrT: 192x192 n-major for proj/recon MFMA.
__launch_bounds__(256)
__global__ void prep_weights_kernel(const float* __restrict__ w_qkv,
                                    const float* __restrict__ w_g1,
                                    const float* __restrict__ w_g2,
                                    const float* __restrict__ w_proj,
                                    const float* __restrict__ w_rec,
                                    ushort* __restrict__ WqkvT,
                                    ushort* __restrict__ W1T,
                                    ushort* __restrict__ W2C,
                                    ushort* __restrict__ WpT,
                                    ushort* __restrict__ WrT) {
    int idx = blockIdx.x * 256 + threadIdx.x;
    if (idx < 576 * 192) {
        int n = idx / 192, k = idx % 192;
        WqkvT[idx] = f2bf(w_qkv[(size_t)k * C3 + n]);
    }
    if (idx < 768 * 192) {
        int n = idx / 192, k = idx % 192;
        W1T[idx] = f2bf(w_g1[(size_t)k * C4 + n]);
    }
    if (idx < 192 * 768) {
        int hc = idx / 12288, rem = idx % 12288;
        int n = rem / 64, kloc = rem & 63;
        W2C[idx] = f2bf(w_g2[(size_t)(hc * 64 + kloc) * CDIM + n]);
    }
    if (idx < 192 * 192) {
        int n = idx / 192, k = idx % 192;
        WpT[idx] = f2bf(w_proj[(size_t)k * CDIM + n]);
        WrT[idx] = f2bf(w_rec[(size_t)k * CDIM + n]);
    }
}

// ---------------------------------------------------------------------------
// K1: 1x1 conv == per-batch GEMM (fp32)
__launch_bounds__(256)
__global__ void conv1x1_kernel(const float* __restrict__ x,
                               const float* __restrict__ w1,
                               const float* __restrict__ b1,
                               float* __restrict__ f1) {
    __shared__ __align__(16) float As[16][68];
    __shared__ __align__(16) float Bs[16][64];
    const int tid = threadIdx.x;
    const int p0 = blockIdx.x * 64;
    const int m0 = blockIdx.y * 64;
    const int b  = blockIdx.z;
    const int tm = tid >> 4, tn = tid & 15;
    const int mload = tid >> 2, kload = (tid & 3) * 4;
    const int kw = tid >> 4, nw = (tid & 15) * 4;
    float acc[4][4] = {};
    const float* xb = x + (size_t)b * CDIM * HWSZ;
    for (int k0 = 0; k0 < CDIM; k0 += 16) {
        float4 av = *(const float4*)&w1[(size_t)(m0 + mload) * CDIM + k0 + kload];
        float4 bv = *(const float4*)&xb[(size_t)(k0 + kw) * HWSZ + p0 + nw];
        __syncthreads();
        As[kload + 0][mload] = av.x;
        As[kload + 1][mload] = av.y;
        As[kload + 2][mload] = av.z;
        As[kload + 3][mload] = av.w;
        *(float4*)&Bs[kw][nw] = bv;
        __syncthreads();
#pragma unroll
        for (int kk = 0; kk < 16; ++kk) {
            float a[4], bb[4];
            *(float4*)a  = *(const float4*)&As[kk][tm * 4];
            *(float4*)bb = *(const float4*)&Bs[kk][tn * 4];
#pragma unroll
            for (int i = 0; i < 4; ++i)
#pragma unroll
                for (int j = 0; j < 4; ++j) acc[i][j] += a[i] * bb[j];
        }
    }
    float* outb = f1 + (size_t)b * CDIM * HWSZ;
#pragma unroll
    for (int i = 0; i < 4; ++i) {
        int m = m0 + tm * 4 + i;
        float bias = b1[m];
        float4 o = make_float4(acc[i][0] + bias, acc[i][1] + bias,
                               acc[i][2] + bias, acc[i][3] + bias);
        *(float4*)&outb[(size_t)m * HWSZ + p0 + tn * 4] = o;
    }
}

// ---------------------------------------------------------------------------
// K2: depthwise 3x3 SAME, NCHW.
__launch_bounds__(256)
__global__ void dwconv_kernel(const float* __restrict__ f1,
                              const float* __restrict__ w_dw,
                              const float* __restrict__ b_dw,
                              float* __restrict__ f2) {
    unsigned int idx = blockIdx.x * 256u + threadIdx.x;
    int w = idx % WDIM;
    unsigned int r = idx / WDIM;
    int h = r % HDIM;
    unsigned int bc = r / HDIM;
    int c = bc % CDIM;
    const float* base = f1 + (size_t)bc * HWSZ;
    const float* wd = w_dw + c * 9;
    float acc = b_dw[c];
#pragma unroll
    for (int ky = 0; ky < 3; ++ky) {
        int hy = h + ky - 1;
        if (hy < 0 || hy >= HDIM) continue;
#pragma unroll
        for (int kx = 0; kx < 3; ++kx) {
            int wx = w + kx - 1;
            if (wx < 0 || wx >= WDIM) continue;
            acc += base[hy * WDIM + wx] * wd[ky * 3 + kx];
        }
    }
    f2[idx] = acc;
}

// ---------------------------------------------------------------------------
// K3: LayerNorm over C + window partition -> token-major pb[M][PBP] (bf16).
__launch_bounds__(256)
__global__ void ln_part_kernel(const float* __restrict__ f2,
                               const float* __restrict__ ln_g,
                               const float* __restrict__ ln_b,
                               ushort* __restrict__ pb) {
    __shared__ float T[CDIM][33];
    __shared__ float Rs[8][32], Rs2[8][32];
    __shared__ float Mu[32], Rsig[32];
    const int tid = threadIdx.x;
    const int wt = blockIdx.x, h = blockIdx.y, b = blockIdx.z;
    const int w0 = wt * 32;
    const size_t rowbase = (size_t)b * CDIM * HWSZ + (size_t)h * WDIM + w0;
    for (int idx = tid; idx < CDIM * 32; idx += 256) {
        int c = idx >> 5, j = idx & 31;
        T[c][j] = f2[rowbase + (size_t)c * HWSZ + j];
    }
    __syncthreads();
    {
        int j = tid & 31, q = tid >> 5;
        float s = 0.f, s2 = 0.f;
#pragma unroll
        for (int i = 0; i < 24; ++i) {
            float v = T[q * 24 + i][j];
            s += v; s2 += v * v;
        }
        Rs[q][j] = s; Rs2[q][j] = s2;
    }
    __syncthreads();
    if (tid < 32) {
        float s = 0.f, s2 = 0.f;
#pragma unroll
        for (int q = 0; q < 8; ++q) { s += Rs[q][tid]; s2 += Rs2[q][tid]; }
        float mu = s * (1.0f / CDIM);
        float var = s2 * (1.0f / CDIM) - mu * mu;
        Mu[tid] = mu;
        Rsig[tid] = rsqrtf(var + LN_EPS);
    }
    __syncthreads();
    const int l = tid & 63;
    const int jo = tid >> 6;
    for (int it = 0; it < 8; ++it) {
        int j = it * 4 + jo;
        int w = w0 + j;
        size_t token = ((size_t)(b * NWH + (h >> 3)) * NWH + (w >> 3)) * TOK
                       + ((h & 7) * 8 + (w & 7));
        float mu = Mu[j], rs = Rsig[j];
#pragma unroll
        for (int rep = 0; rep < 3; ++rep) {
            int c = l + rep * 64;
            pb[token * PBP + c] = f2bf((T[c][j] - mu) * rs * ln_g[c] + ln_b[c]);
        }
    }
}

// ---------------------------------------------------------------------------
// K4: MFMA attention. 1 window (64 tokens) per block, 4 waves.
// launch_bounds(256,3): occupancy is LDS-limited at 3 blocks/CU, so VGPRs up
// to ~168 are free — lets the QKV B-fragment L2 loads stay in flight.
__launch_bounds__(256, 3)
__global__ void attn_mfma_kernel(const ushort* __restrict__ pb,
                                 const ushort* __restrict__ WqkvT,
                                 const float* __restrict__ b_qkv,
                                 float* __restrict__ oa) {
    __shared__ __align__(16) ushort Pt[64 * PBP];    // 25600 B p tile, k-contig
    __shared__ __align__(16) ushort Qb[64 * 40];     //  5120 B Q (scale folded)
    __shared__ __align__(16) ushort Kb[64 * 40];     //  5120 B K
    __shared__ __align__(16) ushort Vt[32 * 72];     //  4608 B V^T (d rows, token-contig)
    __shared__ __align__(16) ushort Pbf[64 * 72];    //  9216 B softmax(P) bf16
    const int tid = threadIdx.x;
    const int lane = tid & 63, wave = tid >> 6;
    const int quad = lane >> 4, l16 = lane & 15;
    const int m0 = wave * 16;
    const size_t tok0 = (size_t)blockIdx.x * 64;

    // stage p tile via global_load_lds (linear copy, pb pitch == Pt pitch)
    {
        char* PtB = (char*)Pt;
        const char* src = (const char*)(pb + tok0 * PBP);
#pragma unroll
        for (int c = 0; c < 6; ++c) {
            int base = (wave * 6 + c) * 1024;
            gload16(PtB + base, src + base + lane * 16);
        }
        if (wave == 0) gload16(PtB + 24576, src + 24576 + lane * 16);
    }
    __syncthreads();

    for (int h = 0; h < HEADS; ++h) {
        const ushort* baseQ = WqkvT + (size_t)(h * 32) * 192;
        const ushort* baseK = WqkvT + (size_t)(192 + h * 32) * 192;
        const ushort* baseV = WqkvT + (size_t)(384 + h * 32) * 192;
        // ---- QKV GEMM for this head: rows m0..m0+16 x 96 cols (Q|K|V) ----
        f32x4 acc[6];
#pragma unroll
        for (int t = 0; t < 6; ++t) acc[t] = (f32x4){0.f, 0.f, 0.f, 0.f};
#pragma unroll
        for (int kk = 0; kk < 6; ++kk) {
            const int ko = kk * 32 + quad * 8;
            // batch all 6 B-fragments (independent loads) before the MFMAs
            bfrag b0 = *(const bfrag*)&baseQ[(size_t)l16 * 192 + ko];
            bfrag b1 = *(const bfrag*)&baseQ[(size_t)(16 + l16) * 192 + ko];
            bfrag b2 = *(const bfrag*)&baseK[(size_t)l16 * 192 + ko];
            bfrag b3 = *(const bfrag*)&baseK[(size_t)(16 + l16) * 192 + ko];
            bfrag b4 = *(const bfrag*)&baseV[(size_t)l16 * 192 + ko];
            bfrag b5 = *(const bfrag*)&baseV[(size_t)(16 + l16) * 192 + ko];
            bfrag a  = *(const bfrag*)&Pt[(m0 + l16) * PBP + ko];
            __builtin_amdgcn_s_setprio(1);
            acc[0] = __builtin_amdgcn_mfma_f32_16x16x32_bf16(a, b0, acc[0], 0, 0, 0);
            acc[1] = __builtin_amdgcn_mfma_f32_16x16x32_bf16(a, b1, acc[1], 0, 0, 0);
            acc[2] = __builtin_amdgcn_mfma_f32_16x16x32_bf16(a, b2, acc[2], 0, 0, 0);
            acc[3] = __builtin_amdgcn_mfma_f32_16x16x32_bf16(a, b3, acc[3], 0, 0, 0);
            acc[4] = __builtin_amdgcn_mfma_f32_16x16x32_bf16(a, b4, acc[4], 0, 0, 0);
            acc[5] = __builtin_amdgcn_mfma_f32_16x16x32_bf16(a, b5, acc[5], 0, 0, 0);
            __builtin_amdgcn_s_setprio(0);
        }
        // write Q (scale folded), K, V^T to LDS
#pragma unroll
        for (int t = 0; t < 2; ++t) {
            float bq = b_qkv[h * 32 + t * 16 + l16];
            float bk = b_qkv[192 + h * 32 + t * 16 + l16];
            float bv = b_qkv[384 + h * 32 + t * 16 + l16];
#pragma unroll
            for (int reg = 0; reg < 4; ++reg) {
                int row = m0 + quad * 4 + reg;
                Qb[row * 40 + t * 16 + l16] = f2bf((acc[t][reg] + bq) * ATTN_SCALE);
                Kb[row * 40 + t * 16 + l16] = f2bf(acc[t + 2][reg] + bk);
                Vt[(t * 16 + l16) * 72 + row] = f2bf(acc[t + 4][reg] + bv);
            }
        }
        __syncthreads();

        // ---- S = Q.K^T (64x64, K=32): 4 col-tiles, 1 MFMA each ----
        f32x4 s[4];
        {
            bfrag aq = *(const bfrag*)&Qb[(m0 + l16) * 40 + quad * 8];
            bfrag k0 = *(const bfrag*)&Kb[(l16) * 40 + quad * 8];
            bfrag k1 = *(const bfrag*)&Kb[(16 + l16) * 40 + quad * 8];
            bfrag k2 = *(const bfrag*)&Kb[(32 + l16) * 40 + quad * 8];
            bfrag k3 = *(const bfrag*)&Kb[(48 + l16) * 40 + quad * 8];
            __builtin_amdgcn_s_setprio(1);
            s[0] = __builtin_amdgcn_mfma_f32_16x16x32_bf16(
                aq, k0, (f32x4){0.f, 0.f, 0.f, 0.f}, 0, 0, 0);
            s[1] = __builtin_amdgcn_mfma_f32_16x16x32_bf16(
                aq, k1, (f32x4){0.f, 0.f, 0.f, 0.f}, 0, 0, 0);
            s[2] = __builtin_amdgcn_mfma_f32_16x16x32_bf16(
                aq, k2, (f32x4){0.f, 0.f, 0.f, 0.f}, 0, 0, 0);
            s[3] = __builtin_amdgcn_mfma_f32_16x16x32_bf16(
                aq, k3, (f32x4){0.f, 0.f, 0.f, 0.f}, 0, 0, 0);
            __builtin_amdgcn_s_setprio(0);
        }
        // ---- softmax per row (row = m0+quad*4+reg)
#pragma unroll
        for (int reg = 0; reg < 4; ++reg) {
            float mx = fmaxf(fmaxf(s[0][reg], s[1][reg]), fmaxf(s[2][reg], s[3][reg]));
            mx = fmaxf(mx, __shfl_xor(mx, 1));
            mx = fmaxf(mx, __shfl_xor(mx, 2));
            mx = fmaxf(mx, __shfl_xor(mx, 4));
            mx = fmaxf(mx, __shfl_xor(mx, 8));
            float e[4], sum = 0.f;
#pragma unroll
            for (int t = 0; t < 4; ++t) { e[t] = __expf(s[t][reg] - mx); sum += e[t]; }
            sum += __shfl_xor(sum, 1);
            sum += __shfl_xor(sum, 2);
            sum += __shfl_xor(sum, 4);
            sum += __shfl_xor(sum, 8);
            float inv = 1.0f / sum;
            int row = m0 + quad * 4 + reg;
#pragma unroll
            for (int t = 0; t < 4; ++t)
                Pbf[row * 72 + t * 16 + l16] = f2bf(e[t] * inv);
        }
        __syncthreads();

        // ---- O = P.V (64x32, K=64): 2 col-tiles x 2 k-steps ----
        f32x4 o[2];
        o[0] = (f32x4){0.f, 0.f, 0.f, 0.f};
        o[1] = (f32x4){0.f, 0.f, 0.f, 0.f};
#pragma unroll
        for (int kk = 0; kk < 2; ++kk) {
            bfrag a  = *(const bfrag*)&Pbf[(m0 + l16) * 72 + kk * 32 + quad * 8];
            bfrag v0 = *(const bfrag*)&Vt[(l16) * 72 + kk * 32 + quad * 8];
            bfrag v1 = *(const bfrag*)&Vt[(16 + l16) * 72 + kk * 32 + quad * 8];
            __builtin_amdgcn_s_setprio(1);
            o[0] = __builtin_amdgcn_mfma_f32_16x16x32_bf16(a, v0, o[0], 0, 0, 0);
            o[1] = __builtin_amdgcn_mfma_f32_16x16x32_bf16(a, v1, o[1], 0, 0, 0);
            __builtin_amdgcn_s_setprio(0);
        }
#pragma unroll
        for (int t = 0; t < 2; ++t) {
            int col = h * 32 + t * 16 + l16;
#pragma unroll
            for (int reg = 0; reg < 4; ++reg) {
                int row = m0 + quad * 4 + reg;
                oa[(tok0 + row) * (size_t)CDIM + col] = o[t][reg];
            }
        }
        __syncthreads();   // protect Qb/Kb/Vt/Pbf before next head's writes
    }
}

// ---------------------------------------------------------------------------
// K5: MFMA GMLP with global_load_lds weight staging (round-6, proven).
__launch_bounds__(256)
__global__ void gmlp_mfma_kernel(const ushort* __restrict__ pb,
                                 const ushort* __restrict__ WvT,
                                 const float* __restrict__ b_qkv,
                                 const ushort* __restrict__ W1T,
                                 const float* __restrict__ b_g1,
                                 const ushort* __restrict__ W2C,
                                 const float* __restrict__ b_g2,
                                 float* __restrict__ a_io) {
    __shared__ __align__(16) ushort Ab[64 * PBP];   // 25600 B: p tile then V
    __shared__ __align__(16) ushort Wb[12288];      // 24576 B linear weight chunk
    __shared__ __align__(16) ushort Hb[64 * 72];    //  9216 B gelu hidden chunk
    const int tid = threadIdx.x;
    const int lane = tid & 63, wave = tid >> 6;
    const int quad = lane >> 4, l16 = lane & 15;
    const int m0 = wave * 16;
    const int sw = (l16 & 7) << 3;      // read-side XOR swizzle (ushort units)
    const size_t tok0 = (size_t)blockIdx.x * 64;

    int srcA[6], srcB[6], dst6[6];
#pragma unroll
    for (int c = 0; c < 6; ++c) {
        int P = (wave * 6 + c) * 1024 + lane * 16;
        dst6[c] = (wave * 6 + c) * 1024;            // wave-uniform LDS base
        int rA = P / 384;                           // A-type: 384B rows (64x192)
        int mA = P - rA * 384;
        srcA[c] = rA * 384 + (mA ^ ((rA & 7) << 4));
        srcB[c] = P ^ (((P >> 7) & 7) << 4);        // B-type: 128B rows (192x64)
    }
    char* WbB = (char*)Wb;
    char* AbB = (char*)Ab;

#define ISSUE_W(SRC, OFFS)                                                    \
    _Pragma("unroll")                                                         \
    for (int c = 0; c < 6; ++c)                                               \
        gload16(WbB + dst6[c], (const char*)(SRC) + OFFS[c]);

    // stage Ab (linear gload) + issue Wv chunk 0
    {
        const char* src = (const char*)(pb + tok0 * PBP);
#pragma unroll
        for (int c = 0; c < 6; ++c)
            gload16(AbB + dst6[c], src + dst6[c] + lane * 16);
        if (wave == 0) gload16(AbB + 24576, src + 24576 + lane * 16);
    }
    ISSUE_W(WvT, srcA);
    __syncthreads();                      // drain: Ab + Wv(0) ready

    f32x4 vacc[12];
#pragma unroll
    for (int i = 0; i < 12; ++i) vacc[i] = (f32x4){0.f, 0.f, 0.f, 0.f};

#define COMPUTE_K192(ACC, BASEI)                                              \
    _Pragma("unroll")                                                         \
    for (int kk = 0; kk < 6; ++kk) {                                          \
        bfrag a = *(const bfrag*)&Ab[(m0 + l16) * PBP + kk * 32 + quad * 8];  \
        _Pragma("unroll")                                                     \
        for (int t = 0; t < 4; ++t) {                                         \
            bfrag b = *(const bfrag*)&Wb[(t * 16 + l16) * 192                 \
                                         + ((kk * 32 + quad * 8) ^ sw)];      \
            ACC[(BASEI) + t] = __builtin_amdgcn_mfma_f32_16x16x32_bf16(       \
                a, b, ACC[(BASEI) + t], 0, 0, 0);                             \
        }                                                                     \
    }

    COMPUTE_K192(vacc, 0);
    __syncthreads();
    ISSUE_W((const char*)WvT + 24576, srcA);
    __syncthreads();
    COMPUTE_K192(vacc, 4);
    __syncthreads();
    ISSUE_W((const char*)WvT + 49152, srcA);
    __syncthreads();
    COMPUTE_K192(vacc, 8);
    // write V (bf16) into this wave's own rows of Ab (wave-private)
#pragma unroll
    for (int i = 0; i < 12; ++i) {
        int n = i * 16 + l16;
        float bias = b_qkv[384 + n];
#pragma unroll
        for (int reg = 0; reg < 4; ++reg) {
            int r = m0 + quad * 4 + reg;
            Ab[r * PBP + n] = f2bf(vacc[i][reg] + bias);
        }
    }
    __syncthreads();
    ISSUE_W(W1T, srcA);
    __syncthreads();

    // ---- hidden loop: 12 chunks of 64 hidden cols ----
    f32x4 acc2[12];
#pragma unroll
    for (int i = 0; i < 12; ++i) acc2[i] = (f32x4){0.f, 0.f, 0.f, 0.f};
    for (int hc = 0; hc < 12; ++hc) {
        f32x4 acc1[4];
#pragma unroll
        for (int t = 0; t < 4; ++t) acc1[t] = (f32x4){0.f, 0.f, 0.f, 0.f};
        COMPUTE_K192(acc1, 0);
#pragma unroll
        for (int t = 0; t < 4; ++t) {
            int n = t * 16 + l16;
            float bb = b_g1[hc * 64 + n];
#pragma unroll
            for (int reg = 0; reg < 4; ++reg) {
                float xv = acc1[t][reg] + bb;
                Hb[(m0 + quad * 4 + reg) * 72 + n] = f2bf(gelu_erf(xv));
            }
        }
        __syncthreads();                  // W1 reads done
        ISSUE_W((const char*)W2C + (size_t)hc * 24576, srcB);
        __syncthreads();                  // W2(hc) ready
#pragma unroll
        for (int kk = 0; kk < 2; ++kk) {
            bfrag a = *(const bfrag*)&Hb[(m0 + l16) * 72 + kk * 32 + quad * 8];
#pragma unroll
            for (int t = 0; t < 12; ++t) {
                bfrag b = *(const bfrag*)&Wb[(t * 16 + l16) * 64
                                             + ((kk * 32 + quad * 8) ^ sw)];
                acc2[t] = __builtin_amdgcn_mfma_f32_16x16x32_bf16(a, b, acc2[t], 0, 0, 0);
            }
        }
        if (hc < 11) {
            __syncthreads();              // W2 reads done
            ISSUE_W((const char*)W1T + (size_t)(hc + 1) * 24576, srcA);
            __syncthreads();              // W1(hc+1) ready
        }
    }
    // epilogue: product with attention output, in place
#pragma unroll
    for (int t = 0; t < 12; ++t) {
        int c = t * 16 + l16;
        float bg = b_g2[c];
#pragma unroll
        for (int reg = 0; reg < 4; ++reg) {
            size_t idx = (tok0 + m0 + quad * 4 + reg) * CDIM + c;
            a_io[idx] *= (acc2[t][reg] + bg);
        }
    }
#undef ISSUE_W
#undef COMPUTE_K192
}

// ---------------------------------------------------------------------------
// K7: MFMA proj+recon (round-7, proven).
__launch_bounds__(256)
__global__ void proj_recon_kernel(const ushort* __restrict__ WpT,
                                  const float* __restrict__ b_proj,
                                  const ushort* __restrict__ WrT,
                                  const float* __restrict__ b_rec,
                                  const ushort* __restrict__ pb,
                                  float* __restrict__ a_io,
                                  float* __restrict__ loss) {
    __shared__ __align__(16) ushort Tb[64 * PBP];   // 25600 B product/F (bf16)
    __shared__ __align__(16) ushort Wb[12288];      // 24576 B weight chunk
    __shared__ float red[256];
    const int tid = threadIdx.x;
    const int lane = tid & 63, wave = tid >> 6;
    const int quad = lane >> 4, l16 = lane & 15;
    const int m0 = wave * 16;
    const int sw = (l16 & 7) << 3;
    const size_t tok0 = (size_t)blockIdx.x * 64;

    int srcA[6], dst6[6];
#pragma unroll
    for (int c = 0; c < 6; ++c) {
        int P = (wave * 6 + c) * 1024 + lane * 16;
        dst6[c] = (wave * 6 + c) * 1024;
        int rA = P / 384;
        int mA = P - rA * 384;
        srcA[c] = rA * 384 + (mA ^ ((rA & 7) << 4));
    }
    char* WbB = (char*)Wb;

#define PR_ISSUE(SRC)                                                         \
    _Pragma("unroll")                                                         \
    for (int c = 0; c < 6; ++c)                                               \
        gload16(WbB + dst6[c], (const char*)(SRC) + srcA[c]);
#define PR_COMPUTE(ACC, BASEI)                                                \
    _Pragma("unroll")                                                         \
    for (int kk = 0; kk < 6; ++kk) {                                          \
        bfrag a = *(const bfrag*)&Tb[(m0 + l16) * PBP + kk * 32 + quad * 8];  \
        _Pragma("unroll")                                                     \
        for (int t = 0; t < 4; ++t) {                                         \
            bfrag b = *(const bfrag*)&Wb[(t * 16 + l16) * 192                 \
                                         + ((kk * 32 + quad * 8) ^ sw)];      \
            ACC[(BASEI) + t] = __builtin_amdgcn_mfma_f32_16x16x32_bf16(       \
                a, b, ACC[(BASEI) + t], 0, 0, 0);                             \
        }                                                                     \
    }

    // stage product tile fp32 -> bf16 Tb; issue Wp chunk 0
    PR_ISSUE(WpT);
    for (int i4 = tid * 4; i4 < 64 * 192; i4 += 1024) {
        float4 v = *(const float4*)&a_io[tok0 * CDIM + i4];
        int r = i4 / 192, c = i4 - r * 192;
        ushort u[4] = { f2bf(v.x), f2bf(v.y), f2bf(v.z), f2bf(v.w) };
        *(uint2*)&Tb[r * PBP + c] = *(uint2*)u;
    }
    __syncthreads();                      // Tb + Wp(0) ready

    // ---- F = product @ w_proj: 3 chunks of 64 N-cols, K=192 ----
    f32x4 facc[12];
#pragma unroll
    for (int i = 0; i < 12; ++i) facc[i] = (f32x4){0.f, 0.f, 0.f, 0.f};
    PR_COMPUTE(facc, 0);
    __syncthreads();
    PR_ISSUE((const char*)WpT + 24576);
    __syncthreads();
    PR_COMPUTE(facc, 4);
    __syncthreads();
    PR_ISSUE((const char*)WpT + 49152);
    __syncthreads();
    PR_COMPUTE(facc, 8);
    // write F: fp32 to a_io, bf16 into own-wave rows of Tb (A for recon)
#pragma unroll
    for (int i = 0; i < 12; ++i) {
        int n = i * 16 + l16;
        float bp = b_proj[n];
#pragma unroll
        for (int reg = 0; reg < 4; ++reg) {
            int r = m0 + quad * 4 + reg;
            float fv = facc[i][reg] + bp;
            a_io[(tok0 + r) * (size_t)CDIM + n] = fv;
            Tb[r * PBP + n] = f2bf(fv);
        }
    }
    __syncthreads();                      // Wp(2) reads done
    PR_ISSUE(WrT);
    __syncthreads();                      // Wr(0) ready

    // ---- R = F @ w_rec: 3 chunks ----
    f32x4 racc[12];
#pragma unroll
    for (int i = 0; i < 12; ++i) racc[i] = (f32x4){0.f, 0.f, 0.f, 0.f};
    PR_COMPUTE(racc, 0);
    __syncthreads();
    PR_ISSUE((const char*)WrT + 24576);
    __syncthreads();
    PR_COMPUTE(racc, 4);
    __syncthreads();
    PR_ISSUE((const char*)WrT + 49152);
    __syncthreads();
    PR_COMPUTE(racc, 8);

    // ---- L1 loss vs pb ----
    float ls = 0.f;
#pragma unroll
    for (int i = 0; i < 12; ++i) {
        int n = i * 16 + l16;
        float br = b_rec[n];
#pragma unroll
        for (int reg = 0; reg < 4; ++reg) {
            int r = m0 + quad * 4 + reg;
            float rv = racc[i][reg] + br;
            ls += fabsf(rv - bf2f(pb[(tok0 + r) * PBP + n]));
        }
    }
    red[tid] = ls;
    __syncthreads();
    for (int s = 128; s > 0; s >>= 1) {
        if (tid < s) red[tid] += red[tid + s];
        __syncthreads();
    }
    if (tid == 0) atomicAdd(loss, red[0] * (0.1f / (float)IMGSZ));
#undef PR_ISSUE
#undef PR_COMPUTE
}

// ---------------------------------------------------------------------------
// K8: window reverse + residual.
__launch_bounds__(256)
__global__ void reverse_res_kernel(const float* __restrict__ fused,
                                   const float* __restrict__ x,
                                   float* __restrict__ out) {
    __shared__ float T[CDIM][33];
    const int tid = threadIdx.x;
    const int wt = blockIdx.x, h = blockIdx.y, b = blockIdx.z;
    const int w0 = wt * 32;
    const int l = tid & 63, jo = tid >> 6;
    for (int it = 0; it < 8; ++it) {
        int j = it * 4 + jo;
        int w = w0 + j;
        size_t token = ((size_t)(b * NWH + (h >> 3)) * NWH + (w >> 3)) * TOK
                       + ((h & 7) * 8 + (w & 7));
#pragma unroll
        for (int rep = 0; rep < 3; ++rep) {
            int c = l + rep * 64;
            T[c][j] = fused[token * CDIM + c];
        }
    }
    __syncthreads();
    const size_t rowbase = (size_t)b * CDIM * HWSZ + (size_t)h * WDIM + w0;
    for (int idx = tid; idx < CDIM * 32; idx += 256) {
        int c = idx >> 5, j = idx & 31;
        size_t gp = rowbase + (size_t)c * HWSZ + j;
        out[gp] = T[c][j] + x[gp];
    }
}

// ---------------------------------------------------------------------------
extern "C" void kernel_launch(void* const* d_in, const int* in_sizes, int n_in,
                              void* d_out, int out_size, void* d_ws, size_t ws_size,
                              hipStream_t stream) {
    const float* x      = (const float*)d_in[0];
    const float* w_pre1 = (const float*)d_in[1];
    const float* b_pre1 = (const float*)d_in[2];
    const float* w_dw   = (const float*)d_in[3];
    const float* b_dw   = (const float*)d_in[4];
    const float* ln_g   = (const float*)d_in[5];
    const float* ln_b   = (const float*)d_in[6];
    const float* w_qkv  = (const float*)d_in[7];
    const float* b_qkv  = (const float*)d_in[8];
    const float* w_proj = (const float*)d_in[9];
    const float* b_proj = (const float*)d_in[10];
    const float* w_g1   = (const float*)d_in[11];
    const float* b_g1   = (const float*)d_in[12];
    const float* w_g2   = (const float*)d_in[13];
    const float* b_g2   = (const float*)d_in[14];
    const float* w_rec  = (const float*)d_in[15];
    const float* b_rec  = (const float*)d_in[16];

    float* OutR = (float*)d_out;
    float* loss = OutR + (size_t)IMGSZ;
    float* A    = (float*)d_ws;            // 154 MB fp32 region

    // d_out layout during pipeline (front->back):
    //  [f1 fp32 full]  ->  [pb bf16 (pitch 200) ~80MB | bf16 weights ~1MB]
    //  final: out fp32 full + loss scalar
    ushort* pb    = (ushort*)d_out;                    // MTOK*PBP bf16
    ushort* WqkvT = pb    + (size_t)MTOK * PBP;        // 576x192 (n-major, k-contig)
    ushort* W1T   = WqkvT + 576 * 192;                 // 768x192
    ushort* W2C   = W1T   + 768 * 192;                 // [12][192][64] chunk-contig
    ushort* WpT   = W2C   + 192 * 768;                 // 192x192
    ushort* WrT   = WpT   + 192 * 192;                 // 192x192
    ushort* WvT   = WqkvT + 384 * 192;                 // V rows of WqkvT (for gmlp)

    hipMemsetAsync(loss, 0, sizeof(float), stream);

    // K1: f1 = conv1x1(x) -> d_out (fp32)
    conv1x1_kernel<<<dim3(HWSZ / 64, CDIM / 64, BATCH), 256, 0, stream>>>(
        x, w_pre1, b_pre1, OutR);
    // K2: f2 = dwconv(f1) -> A
    dwconv_kernel<<<IMGSZ / 256, 256, 0, stream>>>(OutR, w_dw, b_dw, A);
    // prep bf16 weights (after f1 is dead)
    prep_weights_kernel<<<(768 * 192 + 255) / 256, 256, 0, stream>>>(
        w_qkv, w_g1, w_g2, w_proj, w_rec, WqkvT, W1T, W2C, WpT, WrT);
    // K3: pb = LN+partition(f2) -> d_out front (bf16, pitch PBP)
    ln_part_kernel<<<dim3(WDIM / 32, HDIM, BATCH), 256, 0, stream>>>(
        A, ln_g, ln_b, pb);
    // K4: MFMA attention -> A
    attn_mfma_kernel<<<NWIN, 256, 0, stream>>>(pb, WqkvT, b_qkv, A);
    // K5: A = attn .* gmlp(v) in place (MFMA, gload_lds staging)
    gmlp_mfma_kernel<<<MTOK / 64, 256, 0, stream>>>(
        pb, WvT, b_qkv, W1T, b_g1, W2C, b_g2, A);
    // K7: A = product @ w_proj + b (in place, MFMA); recon loss vs pb
    proj_recon_kernel<<<MTOK / 64, 256, 0, stream>>>(
        WpT, b_proj, WrT, b_rec, pb, A, loss);
    // K8: out = reverse(A) + x -> d_out
    reverse_res_kernel<<<dim3(WDIM / 32, HDIM, BATCH), 256, 0, stream>>>(
        A, x, OutR);
}

// Round 9
// 1540.728 us; speedup vs baseline: 1.0378x; 1.0378x over previous
//
#include <hip/hip_runtime.h>
#include <hip/hip_bf16.h>
#include <math.h>

// Problem constants
#define BATCH 4
#define CDIM 192
#define HDIM 224
#define WDIM 224
#define HWSZ (HDIM * WDIM)            // 50176
#define NWH 28                        // 224/8
#define NWIN (BATCH * NWH * NWH)      // 3136
#define TOK 64
#define MTOK (NWIN * TOK)             // 200704
#define HEADS 6
#define C3 (3 * CDIM)                 // 576
#define C4 (4 * CDIM)                 // 768
#define IMGSZ (BATCH * CDIM * HWSZ)   // 38535168
#define ATTN_SCALE 0.17677669529663687f
#define LN_EPS 1e-6f
#define PBP 200                        // pb row pitch (ushorts), 400 B, 16B-aligned

typedef __attribute__((ext_vector_type(8))) short bfrag;   // 8 bf16 (4 VGPRs)
typedef __attribute__((ext_vector_type(4))) float f32x4;

__device__ __forceinline__ float bf2f(unsigned short u) {
    union { unsigned int i; float f; } v; v.i = ((unsigned int)u) << 16; return v.f;
}
__device__ __forceinline__ unsigned short f2bf(float f) {
    union { unsigned int i; float f; } v; v.f = f;
    unsigned int r = (v.i + 0x7FFFu + ((v.i >> 16) & 1u)) >> 16;   // RNE
    return (unsigned short)r;
}
// exact-erf GELU via Abramowitz-Stegun 7.1.26 (|erf err| <= 1.5e-7)
__device__ __forceinline__ float gelu_erf(float x) {
    float z = fabsf(x) * 0.70710678118654752f;
    float t = __fdividef(1.0f, 1.0f + 0.3275911f * z);
    float poly = t * (0.254829592f + t * (-0.284496736f +
                 t * (1.421413741f + t * (-1.453152027f + t * 1.061405429f))));
    float erfv = 1.0f - poly * __expf(-z * z);
    erfv = (x < 0.f) ? -erfv : erfv;
    return 0.5f * x * (1.0f + erfv);
}
// async global->LDS, 16B per lane; LDS dest = uniform base + lane*16 (HW)
__device__ __forceinline__ void gload16(void* lds, const void* g) {
    __builtin_amdgcn_global_load_lds(
        (const __attribute__((address_space(1))) void*)g,
        (__attribute__((address_space(3))) void*)lds, 16, 0, 0);
}

// ---------------------------------------------------------------------------
// Prep: transpose+convert weights to bf16 (n-major, k-contiguous) once/launch.
__launch_bounds__(256)
__global__ void prep_weights_kernel(const float* __restrict__ w_qkv,
                                    const float* __restrict__ w_g1,
                                    const float* __restrict__ w_g2,
                                    const float* __restrict__ w_proj,
                                    const float* __restrict__ w_rec,
                                    ushort* __restrict__ WqkvT,
                                    ushort* __restrict__ W1T,
                                    ushort* __restrict__ W2C,
                                    ushort* __restrict__ WpT,
                                    ushort* __restrict__ WrT) {
    int idx = blockIdx.x * 256 + threadIdx.x;
    if (idx < 576 * 192) {
        int n = idx / 192, k = idx % 192;
        WqkvT[idx] = f2bf(w_qkv[(size_t)k * C3 + n]);
    }
    if (idx < 768 * 192) {
        int n = idx / 192, k = idx % 192;
        W1T[idx] = f2bf(w_g1[(size_t)k * C4 + n]);
    }
    if (idx < 192 * 768) {
        int hc = idx / 12288, rem = idx % 12288;
        int n = rem / 64, kloc = rem & 63;
        W2C[idx] = f2bf(w_g2[(size_t)(hc * 64 + kloc) * CDIM + n]);
    }
    if (idx < 192 * 192) {
        int n = idx / 192, k = idx % 192;
        WpT[idx] = f2bf(w_proj[(size_t)k * CDIM + n]);
        WrT[idx] = f2bf(w_rec[(size_t)k * CDIM + n]);
    }
}

// ---------------------------------------------------------------------------
// K1: 1x1 conv == per-batch GEMM (fp32)
__launch_bounds__(256)
__global__ void conv1x1_kernel(const float* __restrict__ x,
                               const float* __restrict__ w1,
                               const float* __restrict__ b1,
                               float* __restrict__ f1) {
    __shared__ __align__(16) float As[16][68];
    __shared__ __align__(16) float Bs[16][64];
    const int tid = threadIdx.x;
    const int p0 = blockIdx.x * 64;
    const int m0 = blockIdx.y * 64;
    const int b  = blockIdx.z;
    const int tm = tid >> 4, tn = tid & 15;
    const int mload = tid >> 2, kload = (tid & 3) * 4;
    const int kw = tid >> 4, nw = (tid & 15) * 4;
    float acc[4][4] = {};
    const float* xb = x + (size_t)b * CDIM * HWSZ;
    for (int k0 = 0; k0 < CDIM; k0 += 16) {
        float4 av = *(const float4*)&w1[(size_t)(m0 + mload) * CDIM + k0 + kload];
        float4 bv = *(const float4*)&xb[(size_t)(k0 + kw) * HWSZ + p0 + nw];
        __syncthreads();
        As[kload + 0][mload] = av.x;
        As[kload + 1][mload] = av.y;
        As[kload + 2][mload] = av.z;
        As[kload + 3][mload] = av.w;
        *(float4*)&Bs[kw][nw] = bv;
        __syncthreads();
#pragma unroll
        for (int kk = 0; kk < 16; ++kk) {
            float a[4], bb[4];
            *(float4*)a  = *(const float4*)&As[kk][tm * 4];
            *(float4*)bb = *(const float4*)&Bs[kk][tn * 4];
#pragma unroll
            for (int i = 0; i < 4; ++i)
#pragma unroll
                for (int j = 0; j < 4; ++j) acc[i][j] += a[i] * bb[j];
        }
    }
    float* outb = f1 + (size_t)b * CDIM * HWSZ;
#pragma unroll
    for (int i = 0; i < 4; ++i) {
        int m = m0 + tm * 4 + i;
        float bias = b1[m];
        float4 o = make_float4(acc[i][0] + bias, acc[i][1] + bias,
                               acc[i][2] + bias, acc[i][3] + bias);
        *(float4*)&outb[(size_t)m * HWSZ + p0 + tn * 4] = o;
    }
}

// ---------------------------------------------------------------------------
// K2: depthwise 3x3 SAME, NCHW.
__launch_bounds__(256)
__global__ void dwconv_kernel(const float* __restrict__ f1,
                              const float* __restrict__ w_dw,
                              const float* __restrict__ b_dw,
                              float* __restrict__ f2) {
    unsigned int idx = blockIdx.x * 256u + threadIdx.x;
    int w = idx % WDIM;
    unsigned int r = idx / WDIM;
    int h = r % HDIM;
    unsigned int bc = r / HDIM;
    int c = bc % CDIM;
    const float* base = f1 + (size_t)bc * HWSZ;
    const float* wd = w_dw + c * 9;
    float acc = b_dw[c];
#pragma unroll
    for (int ky = 0; ky < 3; ++ky) {
        int hy = h + ky - 1;
        if (hy < 0 || hy >= HDIM) continue;
#pragma unroll
        for (int kx = 0; kx < 3; ++kx) {
            int wx = w + kx - 1;
            if (wx < 0 || wx >= WDIM) continue;
            acc += base[hy * WDIM + wx] * wd[ky * 3 + kx];
        }
    }
    f2[idx] = acc;
}

// ---------------------------------------------------------------------------
// K3: LayerNorm over C + window partition -> token-major pb[M][PBP] (bf16).
__launch_bounds__(256)
__global__ void ln_part_kernel(const float* __restrict__ f2,
                               const float* __restrict__ ln_g,
                               const float* __restrict__ ln_b,
                               ushort* __restrict__ pb) {
    __shared__ float T[CDIM][33];
    __shared__ float Rs[8][32], Rs2[8][32];
    __shared__ float Mu[32], Rsig[32];
    const int tid = threadIdx.x;
    const int wt = blockIdx.x, h = blockIdx.y, b = blockIdx.z;
    const int w0 = wt * 32;
    const size_t rowbase = (size_t)b * CDIM * HWSZ + (size_t)h * WDIM + w0;
    for (int idx = tid; idx < CDIM * 32; idx += 256) {
        int c = idx >> 5, j = idx & 31;
        T[c][j] = f2[rowbase + (size_t)c * HWSZ + j];
    }
    __syncthreads();
    {
        int j = tid & 31, q = tid >> 5;
        float s = 0.f, s2 = 0.f;
#pragma unroll
        for (int i = 0; i < 24; ++i) {
            float v = T[q * 24 + i][j];
            s += v; s2 += v * v;
        }
        Rs[q][j] = s; Rs2[q][j] = s2;
    }
    __syncthreads();
    if (tid < 32) {
        float s = 0.f, s2 = 0.f;
#pragma unroll
        for (int q = 0; q < 8; ++q) { s += Rs[q][tid]; s2 += Rs2[q][tid]; }
        float mu = s * (1.0f / CDIM);
        float var = s2 * (1.0f / CDIM) - mu * mu;
        Mu[tid] = mu;
        Rsig[tid] = rsqrtf(var + LN_EPS);
    }
    __syncthreads();
    const int l = tid & 63;
    const int jo = tid >> 6;
    for (int it = 0; it < 8; ++it) {
        int j = it * 4 + jo;
        int w = w0 + j;
        size_t token = ((size_t)(b * NWH + (h >> 3)) * NWH + (w >> 3)) * TOK
                       + ((h & 7) * 8 + (w & 7));
        float mu = Mu[j], rs = Rsig[j];
#pragma unroll
        for (int rep = 0; rep < 3; ++rep) {
            int c = l + rep * 64;
            pb[token * PBP + c] = f2bf((T[c][j] - mu) * rs * ln_g[c] + ln_b[c]);
        }
    }
}

// ---------------------------------------------------------------------------
// K456: MEGA kernel — attention + gMLP + proj + recon, 1 window (64 tokens)
// per block, 4 waves. Fuses the three proven per-window kernels:
//  - attn (r8 body): O accumulates in oacc[12] regs (no oa buffer); V packed
//    into vpk regs (replaces gmlp's v-GEMM entirely — identical values).
//  - gmlp hidden loop (r6 body, gload_lds + both-sides swizzle): acc2[12].
//  - product = oacc * (g + b_g2) in regs -> bf16 into Ab (pb dead).
//  - proj/recon (r7 body): F fp32 -> Fout (workspace), loss vs pb.
// LDS: Ab 25600 + blob(union: attn bufs 24064 | Wb 24576 + Hb 9216) + red.
__launch_bounds__(256)
__global__ void mega_kernel(const ushort* __restrict__ pb,
                            const ushort* __restrict__ WqkvT,
                            const float* __restrict__ b_qkv,
                            const ushort* __restrict__ W1T,
                            const float* __restrict__ b_g1,
                            const ushort* __restrict__ W2C,
                            const float* __restrict__ b_g2,
                            const ushort* __restrict__ WpT,
                            const float* __restrict__ b_proj,
                            const ushort* __restrict__ WrT,
                            const float* __restrict__ b_rec,
                            float* __restrict__ Fout,
                            float* __restrict__ loss) {
    __shared__ __align__(16) ushort Ab[64 * PBP];   // 25600 B: pb -> V -> prod -> F
    __shared__ __align__(16) ushort Blob[16896];    // 33792 B union region
    __shared__ float red[256];
    // attn-phase aliases (first 24064 B of Blob)
    ushort* Qb  = Blob;                 // 64*40 = 2560
    ushort* Kb  = Blob + 2560;          // 64*40 = 2560
    ushort* Vt  = Blob + 5120;          // 32*72 = 2304
    ushort* Pbf = Blob + 7424;          // 64*72 = 4608
    // gmlp/proj-phase aliases
    ushort* Wb  = Blob;                 // 12288 ushorts = 24576 B
    ushort* Hb  = Blob + 12288;         // 64*72 = 4608

    const int tid = threadIdx.x;
    const int lane = tid & 63, wave = tid >> 6;
    const int quad = lane >> 4, l16 = lane & 15;
    const int m0 = wave * 16;
    const int sw = (l16 & 7) << 3;      // read-side XOR swizzle (ushort units)
    const size_t tok0 = (size_t)blockIdx.x * 64;

    int srcA[6], srcB[6], dst6[6];
#pragma unroll
    for (int c = 0; c < 6; ++c) {
        int P = (wave * 6 + c) * 1024 + lane * 16;
        dst6[c] = (wave * 6 + c) * 1024;            // wave-uniform LDS base
        int rA = P / 384;                           // A-type: 384B rows (64x192)
        int mA = P - rA * 384;
        srcA[c] = rA * 384 + (mA ^ ((rA & 7) << 4));
        srcB[c] = P ^ (((P >> 7) & 7) << 4);        // B-type: 128B rows (192x64)
    }
    char* WbB = (char*)Wb;
    char* AbB = (char*)Ab;

#define ISSUE_W(SRC, OFFS)                                                    \
    _Pragma("unroll")                                                         \
    for (int c = 0; c < 6; ++c)                                               \
        gload16(WbB + dst6[c], (const char*)(SRC) + OFFS[c]);
#define COMPUTE_K192(ACC, BASEI)                                              \
    _Pragma("unroll")                                                         \
    for (int kk = 0; kk < 6; ++kk) {                                          \
        bfrag a = *(const bfrag*)&Ab[(m0 + l16) * PBP + kk * 32 + quad * 8];  \
        _Pragma("unroll")                                                     \
        for (int t = 0; t < 4; ++t) {                                         \
            bfrag b = *(const bfrag*)&Wb[(t * 16 + l16) * 192                 \
                                         + ((kk * 32 + quad * 8) ^ sw)];      \
            ACC[(BASEI) + t] = __builtin_amdgcn_mfma_f32_16x16x32_bf16(       \
                a, b, ACC[(BASEI) + t], 0, 0, 0);                             \
        }                                                                     \
    }

    // ---- stage pb tile into Ab (linear gload, pitch PBP) ----
    {
        const char* src = (const char*)(pb + tok0 * PBP);
#pragma unroll
        for (int c = 0; c < 6; ++c)
            gload16(AbB + dst6[c], src + dst6[c] + lane * 16);
        if (wave == 0) gload16(AbB + 24576, src + 24576 + lane * 16);
    }
    __syncthreads();

    // =========================== ATTENTION PHASE ===========================
    f32x4 oacc[12];
#pragma unroll
    for (int i = 0; i < 12; ++i) oacc[i] = (f32x4){0.f, 0.f, 0.f, 0.f};
    unsigned int vpk[12][2];            // packed bf16 V fragments (24 VGPR)

#pragma unroll
    for (int h = 0; h < HEADS; ++h) {
        const ushort* baseQ = WqkvT + (size_t)(h * 32) * 192;
        const ushort* baseK = WqkvT + (size_t)(192 + h * 32) * 192;
        const ushort* baseV = WqkvT + (size_t)(384 + h * 32) * 192;
        f32x4 acc[6];
#pragma unroll
        for (int t = 0; t < 6; ++t) acc[t] = (f32x4){0.f, 0.f, 0.f, 0.f};
#pragma unroll
        for (int kk = 0; kk < 6; ++kk) {
            const int ko = kk * 32 + quad * 8;
            bfrag b0 = *(const bfrag*)&baseQ[(size_t)l16 * 192 + ko];
            bfrag b1 = *(const bfrag*)&baseQ[(size_t)(16 + l16) * 192 + ko];
            bfrag b2 = *(const bfrag*)&baseK[(size_t)l16 * 192 + ko];
            bfrag b3 = *(const bfrag*)&baseK[(size_t)(16 + l16) * 192 + ko];
            bfrag b4 = *(const bfrag*)&baseV[(size_t)l16 * 192 + ko];
            bfrag b5 = *(const bfrag*)&baseV[(size_t)(16 + l16) * 192 + ko];
            bfrag a  = *(const bfrag*)&Ab[(m0 + l16) * PBP + ko];
            __builtin_amdgcn_s_setprio(1);
            acc[0] = __builtin_amdgcn_mfma_f32_16x16x32_bf16(a, b0, acc[0], 0, 0, 0);
            acc[1] = __builtin_amdgcn_mfma_f32_16x16x32_bf16(a, b1, acc[1], 0, 0, 0);
            acc[2] = __builtin_amdgcn_mfma_f32_16x16x32_bf16(a, b2, acc[2], 0, 0, 0);
            acc[3] = __builtin_amdgcn_mfma_f32_16x16x32_bf16(a, b3, acc[3], 0, 0, 0);
            acc[4] = __builtin_amdgcn_mfma_f32_16x16x32_bf16(a, b4, acc[4], 0, 0, 0);
            acc[5] = __builtin_amdgcn_mfma_f32_16x16x32_bf16(a, b5, acc[5], 0, 0, 0);
            __builtin_amdgcn_s_setprio(0);
        }
        // write Q (scale folded), K, V^T to LDS; save V bf16 into vpk regs
#pragma unroll
        for (int t = 0; t < 2; ++t) {
            float bq = b_qkv[h * 32 + t * 16 + l16];
            float bk = b_qkv[192 + h * 32 + t * 16 + l16];
            float bv = b_qkv[384 + h * 32 + t * 16 + l16];
            ushort vb[4];
#pragma unroll
            for (int reg = 0; reg < 4; ++reg) {
                int row = m0 + quad * 4 + reg;
                Qb[row * 40 + t * 16 + l16] = f2bf((acc[t][reg] + bq) * ATTN_SCALE);
                Kb[row * 40 + t * 16 + l16] = f2bf(acc[t + 2][reg] + bk);
                ushort vv = f2bf(acc[t + 4][reg] + bv);
                Vt[(t * 16 + l16) * 72 + row] = vv;
                vb[reg] = vv;
            }
            vpk[h * 2 + t][0] = (unsigned int)vb[0] | ((unsigned int)vb[1] << 16);
            vpk[h * 2 + t][1] = (unsigned int)vb[2] | ((unsigned int)vb[3] << 16);
        }
        __syncthreads();

        // ---- S = Q.K^T ----
        f32x4 s[4];
        {
            bfrag aq = *(const bfrag*)&Qb[(m0 + l16) * 40 + quad * 8];
            bfrag k0 = *(const bfrag*)&Kb[(l16) * 40 + quad * 8];
            bfrag k1 = *(const bfrag*)&Kb[(16 + l16) * 40 + quad * 8];
            bfrag k2 = *(const bfrag*)&Kb[(32 + l16) * 40 + quad * 8];
            bfrag k3 = *(const bfrag*)&Kb[(48 + l16) * 40 + quad * 8];
            __builtin_amdgcn_s_setprio(1);
            s[0] = __builtin_amdgcn_mfma_f32_16x16x32_bf16(
                aq, k0, (f32x4){0.f, 0.f, 0.f, 0.f}, 0, 0, 0);
            s[1] = __builtin_amdgcn_mfma_f32_16x16x32_bf16(
                aq, k1, (f32x4){0.f, 0.f, 0.f, 0.f}, 0, 0, 0);
            s[2] = __builtin_amdgcn_mfma_f32_16x16x32_bf16(
                aq, k2, (f32x4){0.f, 0.f, 0.f, 0.f}, 0, 0, 0);
            s[3] = __builtin_amdgcn_mfma_f32_16x16x32_bf16(
                aq, k3, (f32x4){0.f, 0.f, 0.f, 0.f}, 0, 0, 0);
            __builtin_amdgcn_s_setprio(0);
        }
        // ---- softmax per row ----
#pragma unroll
        for (int reg = 0; reg < 4; ++reg) {
            float mx = fmaxf(fmaxf(s[0][reg], s[1][reg]), fmaxf(s[2][reg], s[3][reg]));
            mx = fmaxf(mx, __shfl_xor(mx, 1));
            mx = fmaxf(mx, __shfl_xor(mx, 2));
            mx = fmaxf(mx, __shfl_xor(mx, 4));
            mx = fmaxf(mx, __shfl_xor(mx, 8));
            float e[4], sum = 0.f;
#pragma unroll
            for (int t = 0; t < 4; ++t) { e[t] = __expf(s[t][reg] - mx); sum += e[t]; }
            sum += __shfl_xor(sum, 1);
            sum += __shfl_xor(sum, 2);
            sum += __shfl_xor(sum, 4);
            sum += __shfl_xor(sum, 8);
            float inv = 1.0f / sum;
            int row = m0 + quad * 4 + reg;
#pragma unroll
            for (int t = 0; t < 4; ++t)
                Pbf[row * 72 + t * 16 + l16] = f2bf(e[t] * inv);
        }
        __syncthreads();

        // ---- O = P.V -> oacc[h*2 + t] ----
#pragma unroll
        for (int kk = 0; kk < 2; ++kk) {
            bfrag a  = *(const bfrag*)&Pbf[(m0 + l16) * 72 + kk * 32 + quad * 8];
            bfrag v0 = *(const bfrag*)&Vt[(l16) * 72 + kk * 32 + quad * 8];
            bfrag v1 = *(const bfrag*)&Vt[(16 + l16) * 72 + kk * 32 + quad * 8];
            __builtin_amdgcn_s_setprio(1);
            oacc[h * 2 + 0] = __builtin_amdgcn_mfma_f32_16x16x32_bf16(
                a, v0, oacc[h * 2 + 0], 0, 0, 0);
            oacc[h * 2 + 1] = __builtin_amdgcn_mfma_f32_16x16x32_bf16(
                a, v1, oacc[h * 2 + 1], 0, 0, 0);
            __builtin_amdgcn_s_setprio(0);
        }
        __syncthreads();   // protect Qb/Kb/Vt/Pbf before next head's writes
    }

    // ========================== GMLP PHASE =================================
    // write V (bf16, from vpk) into own-wave rows of Ab — pb is dead.
#pragma unroll
    for (int i = 0; i < 12; ++i) {
        int n = i * 16 + l16;
        Ab[(m0 + quad * 4 + 0) * PBP + n] = (ushort)(vpk[i][0] & 0xFFFF);
        Ab[(m0 + quad * 4 + 1) * PBP + n] = (ushort)(vpk[i][0] >> 16);
        Ab[(m0 + quad * 4 + 2) * PBP + n] = (ushort)(vpk[i][1] & 0xFFFF);
        Ab[(m0 + quad * 4 + 3) * PBP + n] = (ushort)(vpk[i][1] >> 16);
    }
    ISSUE_W(W1T, srcA);                 // Wb overwrites attn bufs (dead)
    __syncthreads();                    // W1(0) ready; V writes drained

    f32x4 acc2[12];
#pragma unroll
    for (int i = 0; i < 12; ++i) acc2[i] = (f32x4){0.f, 0.f, 0.f, 0.f};
    for (int hc = 0; hc < 12; ++hc) {
        f32x4 acc1[4];
#pragma unroll
        for (int t = 0; t < 4; ++t) acc1[t] = (f32x4){0.f, 0.f, 0.f, 0.f};
        COMPUTE_K192(acc1, 0);
#pragma unroll
        for (int t = 0; t < 4; ++t) {
            int n = t * 16 + l16;
            float bb = b_g1[hc * 64 + n];
#pragma unroll
            for (int reg = 0; reg < 4; ++reg) {
                float xv = acc1[t][reg] + bb;
                Hb[(m0 + quad * 4 + reg) * 72 + n] = f2bf(gelu_erf(xv));
            }
        }
        __syncthreads();                  // W1 reads done
        ISSUE_W((const char*)W2C + (size_t)hc * 24576, srcB);
        __syncthreads();                  // W2(hc) ready
#pragma unroll
        for (int kk = 0; kk < 2; ++kk) {
            bfrag a = *(const bfrag*)&Hb[(m0 + l16) * 72 + kk * 32 + quad * 8];
#pragma unroll
            for (int t = 0; t < 12; ++t) {
                bfrag b = *(const bfrag*)&Wb[(t * 16 + l16) * 64
                                             + ((kk * 32 + quad * 8) ^ sw)];
                acc2[t] = __builtin_amdgcn_mfma_f32_16x16x32_bf16(a, b, acc2[t], 0, 0, 0);
            }
        }
        if (hc < 11) {
            __syncthreads();              // W2 reads done
            ISSUE_W((const char*)W1T + (size_t)(hc + 1) * 24576, srcA);
            __syncthreads();              // W1(hc+1) ready
        }
    }
    // product = oacc * (g + b_g2) -> bf16 into own-wave rows of Ab (V dead)
#pragma unroll
    for (int t = 0; t < 12; ++t) {
        int c = t * 16 + l16;
        float bg = b_g2[c];
#pragma unroll
        for (int reg = 0; reg < 4; ++reg) {
            int r = m0 + quad * 4 + reg;
            Ab[r * PBP + c] = f2bf(oacc[t][reg] * (acc2[t][reg] + bg));
        }
    }
    __syncthreads();                      // W2 reads done before Wb overwrite
    ISSUE_W(WpT, srcA);
    __syncthreads();                      // Wp(0) ready; product drained

    // ========================== PROJ / RECON PHASE =========================
    f32x4 facc[12];
#pragma unroll
    for (int i = 0; i < 12; ++i) facc[i] = (f32x4){0.f, 0.f, 0.f, 0.f};
    COMPUTE_K192(facc, 0);
    __syncthreads();
    ISSUE_W((const char*)WpT + 24576, srcA);
    __syncthreads();
    COMPUTE_K192(facc, 4);
    __syncthreads();
    ISSUE_W((const char*)WpT + 49152, srcA);
    __syncthreads();
    COMPUTE_K192(facc, 8);
    // write F: fp32 to Fout (for K8), bf16 into own-wave rows of Ab (recon A)
#pragma unroll
    for (int i = 0; i < 12; ++i) {
        int n = i * 16 + l16;
        float bp = b_proj[n];
#pragma unroll
        for (int reg = 0; reg < 4; ++reg) {
            int r = m0 + quad * 4 + reg;
            float fv = facc[i][reg] + bp;
            Fout[(tok0 + r) * (size_t)CDIM + n] = fv;
            Ab[r * PBP + n] = f2bf(fv);
        }
    }
    __syncthreads();                      // Wp(2) reads done
    ISSUE_W(WrT, srcA);
    __syncthreads();                      // Wr(0) ready

    f32x4 racc[12];
#pragma unroll
    for (int i = 0; i < 12; ++i) racc[i] = (f32x4){0.f, 0.f, 0.f, 0.f};
    COMPUTE_K192(racc, 0);
    __syncthreads();
    ISSUE_W((const char*)WrT + 24576, srcA);
    __syncthreads();
    COMPUTE_K192(racc, 4);
    __syncthreads();
    ISSUE_W((const char*)WrT + 49152, srcA);
    __syncthreads();
    COMPUTE_K192(racc, 8);

    // ---- L1 loss vs pb ----
    float ls = 0.f;
#pragma unroll
    for (int i = 0; i < 12; ++i) {
        int n = i * 16 + l16;
        float br = b_rec[n];
#pragma unroll
        for (int reg = 0; reg < 4; ++reg) {
            int r = m0 + quad * 4 + reg;
            float rv = racc[i][reg] + br;
            ls += fabsf(rv - bf2f(pb[(tok0 + r) * PBP + n]));
        }
    }
    red[tid] = ls;
    __syncthreads();
    for (int s = 128; s > 0; s >>= 1) {
        if (tid < s) red[tid] += red[tid + s];
        __syncthreads();
    }
    if (tid == 0) atomicAdd(loss, red[0] * (0.1f / (float)IMGSZ));
#undef ISSUE_W
#undef COMPUTE_K192
}

// ---------------------------------------------------------------------------
// K8: window reverse + residual.
__launch_bounds__(256)
__global__ void reverse_res_kernel(const float* __restrict__ fused,
                                   const float* __restrict__ x,
                                   float* __restrict__ out) {
    __shared__ float T[CDIM][33];
    const int tid = threadIdx.x;
    const int wt = blockIdx.x, h = blockIdx.y, b = blockIdx.z;
    const int w0 = wt * 32;
    const int l = tid & 63, jo = tid >> 6;
    for (int it = 0; it < 8; ++it) {
        int j = it * 4 + jo;
        int w = w0 + j;
        size_t token = ((size_t)(b * NWH + (h >> 3)) * NWH + (w >> 3)) * TOK
                       + ((h & 7) * 8 + (w & 7));
#pragma unroll
        for (int rep = 0; rep < 3; ++rep) {
            int c = l + rep * 64;
            T[c][j] = fused[token * CDIM + c];
        }
    }
    __syncthreads();
    const size_t rowbase = (size_t)b * CDIM * HWSZ + (size_t)h * WDIM + w0;
    for (int idx = tid; idx < CDIM * 32; idx += 256) {
        int c = idx >> 5, j = idx & 31;
        size_t gp = rowbase + (size_t)c * HWSZ + j;
        out[gp] = T[c][j] + x[gp];
    }
}

// ---------------------------------------------------------------------------
extern "C" void kernel_launch(void* const* d_in, const int* in_sizes, int n_in,
                              void* d_out, int out_size, void* d_ws, size_t ws_size,
                              hipStream_t stream) {
    const float* x      = (const float*)d_in[0];
    const float* w_pre1 = (const float*)d_in[1];
    const float* b_pre1 = (const float*)d_in[2];
    const float* w_dw   = (const float*)d_in[3];
    const float* b_dw   = (const float*)d_in[4];
    const float* ln_g   = (const float*)d_in[5];
    const float* ln_b   = (const float*)d_in[6];
    const float* w_qkv  = (const float*)d_in[7];
    const float* b_qkv  = (const float*)d_in[8];
    const float* w_proj = (const float*)d_in[9];
    const float* b_proj = (const float*)d_in[10];
    const float* w_g1   = (const float*)d_in[11];
    const float* b_g1   = (const float*)d_in[12];
    const float* w_g2   = (const float*)d_in[13];
    const float* b_g2   = (const float*)d_in[14];
    const float* w_rec  = (const float*)d_in[15];
    const float* b_rec  = (const float*)d_in[16];

    float* OutR = (float*)d_out;
    float* loss = OutR + (size_t)IMGSZ;
    float* A    = (float*)d_ws;            // 154 MB fp32 region

    // d_out layout during pipeline (front->back):
    //  [f1 fp32 full]  ->  [pb bf16 (pitch 200) ~80MB | bf16 weights ~1MB]
    //  final: out fp32 full + loss scalar
    // d_ws: f2 (154MB) -> F (fused, 154MB)
    ushort* pb    = (ushort*)d_out;                    // MTOK*PBP bf16
    ushort* WqkvT = pb    + (size_t)MTOK * PBP;        // 576x192 (n-major, k-contig)
    ushort* W1T   = WqkvT + 576 * 192;                 // 768x192
    ushort* W2C   = W1T   + 768 * 192;                 // [12][192][64] chunk-contig
    ushort* WpT   = W2C   + 192 * 768;                 // 192x192
    ushort* WrT   = WpT   + 192 * 192;                 // 192x192

    hipMemsetAsync(loss, 0, sizeof(float), stream);

    // K1: f1 = conv1x1(x) -> d_out (fp32)
    conv1x1_kernel<<<dim3(HWSZ / 64, CDIM / 64, BATCH), 256, 0, stream>>>(
        x, w_pre1, b_pre1, OutR);
    // K2: f2 = dwconv(f1) -> A
    dwconv_kernel<<<IMGSZ / 256, 256, 0, stream>>>(OutR, w_dw, b_dw, A);
    // prep bf16 weights (after f1 is dead)
    prep_weights_kernel<<<(768 * 192 + 255) / 256, 256, 0, stream>>>(
        w_qkv, w_g1, w_g2, w_proj, w_rec, WqkvT, W1T, W2C, WpT, WrT);
    // K3: pb = LN+partition(f2) -> d_out front (bf16, pitch PBP)
    ln_part_kernel<<<dim3(WDIM / 32, HDIM, BATCH), 256, 0, stream>>>(
        A, ln_g, ln_b, pb);
    // K456: attention + gmlp + proj + recon fused -> F in A (f2 dead)
    mega_kernel<<<NWIN, 256, 0, stream>>>(
        pb, WqkvT, b_qkv, W1T, b_g1, W2C, b_g2, WpT, b_proj, WrT, b_rec,
        A, loss);
    // K8: out = reverse(F) + x -> d_out (pb/weights dead)
    reverse_res_kernel<<<dim3(WDIM / 32, HDIM, BATCH), 256, 0, stream>>>(
        A, x, OutR);
}

// Round 10
// 1426.720 us; speedup vs baseline: 1.1207x; 1.0799x over previous
//
#include <hip/hip_runtime.h>
#include <hip/hip_bf16.h>
#include <math.h>

// Problem constants
#define BATCH 4
#define CDIM 192
#define HDIM 224
#define WDIM 224
#define HWSZ (HDIM * WDIM)            // 50176
#define NWH 28                        // 224/8
#define NWIN (BATCH * NWH * NWH)      // 3136
#define TOK 64
#define MTOK (NWIN * TOK)             // 200704
#define HEADS 6
#define C3 (3 * CDIM)                 // 576
#define C4 (4 * CDIM)                 // 768
#define IMGSZ (BATCH * CDIM * HWSZ)   // 38535168
#define ATTN_SCALE 0.17677669529663687f
#define LN_EPS 1e-6f
#define PBP 200                        // pb row pitch (ushorts), 400 B, 16B-aligned

typedef __attribute__((ext_vector_type(8))) short bfrag;   // 8 bf16 (4 VGPRs)
typedef __attribute__((ext_vector_type(4))) float f32x4;

__device__ __forceinline__ float bf2f(unsigned short u) {
    union { unsigned int i; float f; } v; v.i = ((unsigned int)u) << 16; return v.f;
}
__device__ __forceinline__ unsigned short f2bf(float f) {
    union { unsigned int i; float f; } v; v.f = f;
    unsigned int r = (v.i + 0x7FFFu + ((v.i >> 16) & 1u)) >> 16;   // RNE
    return (unsigned short)r;
}
// exact-erf GELU via Abramowitz-Stegun 7.1.26 (|erf err| <= 1.5e-7)
__device__ __forceinline__ float gelu_erf(float x) {
    float z = fabsf(x) * 0.70710678118654752f;
    float t = __fdividef(1.0f, 1.0f + 0.3275911f * z);
    float poly = t * (0.254829592f + t * (-0.284496736f +
                 t * (1.421413741f + t * (-1.453152027f + t * 1.061405429f))));
    float erfv = 1.0f - poly * __expf(-z * z);
    erfv = (x < 0.f) ? -erfv : erfv;
    return 0.5f * x * (1.0f + erfv);
}
// async global->LDS, 16B per lane; LDS dest = uniform base + lane*16 (HW)
__device__ __forceinline__ void gload16(void* lds, const void* g) {
    __builtin_amdgcn_global_load_lds(
        (const __attribute__((address_space(1))) void*)g,
        (__attribute__((address_space(3))) void*)lds, 16, 0, 0);
}

// ---------------------------------------------------------------------------
// Prep: transpose+convert weights to bf16 (n-major, k-contiguous) once/launch.
__launch_bounds__(256)
__global__ void prep_weights_kernel(const float* __restrict__ w_qkv,
                                    const float* __restrict__ w_g1,
                                    const float* __restrict__ w_g2,
                                    const float* __restrict__ w_proj,
                                    const float* __restrict__ w_rec,
                                    ushort* __restrict__ WqkvT,
                                    ushort* __restrict__ W1T,
                                    ushort* __restrict__ W2C,
                                    ushort* __restrict__ WpT,
                                    ushort* __restrict__ WrT) {
    int idx = blockIdx.x * 256 + threadIdx.x;
    if (idx < 576 * 192) {
        int n = idx / 192, k = idx % 192;
        WqkvT[idx] = f2bf(w_qkv[(size_t)k * C3 + n]);
    }
    if (idx < 768 * 192) {
        int n = idx / 192, k = idx % 192;
        W1T[idx] = f2bf(w_g1[(size_t)k * C4 + n]);
    }
    if (idx < 192 * 768) {
        int hc = idx / 12288, rem = idx % 12288;
        int n = rem / 64, kloc = rem & 63;
        W2C[idx] = f2bf(w_g2[(size_t)(hc * 64 + kloc) * CDIM + n]);
    }
    if (idx < 192 * 192) {
        int n = idx / 192, k = idx % 192;
        WpT[idx] = f2bf(w_proj[(size_t)k * CDIM + n]);
        WrT[idx] = f2bf(w_rec[(size_t)k * CDIM + n]);
    }
}

// ---------------------------------------------------------------------------
// K1: 1x1 conv == per-batch GEMM (fp32)
__launch_bounds__(256)
__global__ void conv1x1_kernel(const float* __restrict__ x,
                               const float* __restrict__ w1,
                               const float* __restrict__ b1,
                               float* __restrict__ f1) {
    __shared__ __align__(16) float As[16][68];
    __shared__ __align__(16) float Bs[16][64];
    const int tid = threadIdx.x;
    const int p0 = blockIdx.x * 64;
    const int m0 = blockIdx.y * 64;
    const int b  = blockIdx.z;
    const int tm = tid >> 4, tn = tid & 15;
    const int mload = tid >> 2, kload = (tid & 3) * 4;
    const int kw = tid >> 4, nw = (tid & 15) * 4;
    float acc[4][4] = {};
    const float* xb = x + (size_t)b * CDIM * HWSZ;
    for (int k0 = 0; k0 < CDIM; k0 += 16) {
        float4 av = *(const float4*)&w1[(size_t)(m0 + mload) * CDIM + k0 + kload];
        float4 bv = *(const float4*)&xb[(size_t)(k0 + kw) * HWSZ + p0 + nw];
        __syncthreads();
        As[kload + 0][mload] = av.x;
        As[kload + 1][mload] = av.y;
        As[kload + 2][mload] = av.z;
        As[kload + 3][mload] = av.w;
        *(float4*)&Bs[kw][nw] = bv;
        __syncthreads();
#pragma unroll
        for (int kk = 0; kk < 16; ++kk) {
            float a[4], bb[4];
            *(float4*)a  = *(const float4*)&As[kk][tm * 4];
            *(float4*)bb = *(const float4*)&Bs[kk][tn * 4];
#pragma unroll
            for (int i = 0; i < 4; ++i)
#pragma unroll
                for (int j = 0; j < 4; ++j) acc[i][j] += a[i] * bb[j];
        }
    }
    float* outb = f1 + (size_t)b * CDIM * HWSZ;
#pragma unroll
    for (int i = 0; i < 4; ++i) {
        int m = m0 + tm * 4 + i;
        float bias = b1[m];
        float4 o = make_float4(acc[i][0] + bias, acc[i][1] + bias,
                               acc[i][2] + bias, acc[i][3] + bias);
        *(float4*)&outb[(size_t)m * HWSZ + p0 + tn * 4] = o;
    }
}

// ---------------------------------------------------------------------------
// K2: depthwise 3x3 SAME, NCHW.
__launch_bounds__(256)
__global__ void dwconv_kernel(const float* __restrict__ f1,
                              const float* __restrict__ w_dw,
                              const float* __restrict__ b_dw,
                              float* __restrict__ f2) {
    unsigned int idx = blockIdx.x * 256u + threadIdx.x;
    int w = idx % WDIM;
    unsigned int r = idx / WDIM;
    int h = r % HDIM;
    unsigned int bc = r / HDIM;
    int c = bc % CDIM;
    const float* base = f1 + (size_t)bc * HWSZ;
    const float* wd = w_dw + c * 9;
    float acc = b_dw[c];
#pragma unroll
    for (int ky = 0; ky < 3; ++ky) {
        int hy = h + ky - 1;
        if (hy < 0 || hy >= HDIM) continue;
#pragma unroll
        for (int kx = 0; kx < 3; ++kx) {
            int wx = w + kx - 1;
            if (wx < 0 || wx >= WDIM) continue;
            acc += base[hy * WDIM + wx] * wd[ky * 3 + kx];
        }
    }
    f2[idx] = acc;
}

// ---------------------------------------------------------------------------
// K3: LayerNorm over C + window partition -> token-major pb[M][PBP] (bf16).
__launch_bounds__(256)
__global__ void ln_part_kernel(const float* __restrict__ f2,
                               const float* __restrict__ ln_g,
                               const float* __restrict__ ln_b,
                               ushort* __restrict__ pb) {
    __shared__ float T[CDIM][33];
    __shared__ float Rs[8][32], Rs2[8][32];
    __shared__ float Mu[32], Rsig[32];
    const int tid = threadIdx.x;
    const int wt = blockIdx.x, h = blockIdx.y, b = blockIdx.z;
    const int w0 = wt * 32;
    const size_t rowbase = (size_t)b * CDIM * HWSZ + (size_t)h * WDIM + w0;
    for (int idx = tid; idx < CDIM * 32; idx += 256) {
        int c = idx >> 5, j = idx & 31;
        T[c][j] = f2[rowbase + (size_t)c * HWSZ + j];
    }
    __syncthreads();
    {
        int j = tid & 31, q = tid >> 5;
        float s = 0.f, s2 = 0.f;
#pragma unroll
        for (int i = 0; i < 24; ++i) {
            float v = T[q * 24 + i][j];
            s += v; s2 += v * v;
        }
        Rs[q][j] = s; Rs2[q][j] = s2;
    }
    __syncthreads();
    if (tid < 32) {
        float s = 0.f, s2 = 0.f;
#pragma unroll
        for (int q = 0; q < 8; ++q) { s += Rs[q][tid]; s2 += Rs2[q][tid]; }
        float mu = s * (1.0f / CDIM);
        float var = s2 * (1.0f / CDIM) - mu * mu;
        Mu[tid] = mu;
        Rsig[tid] = rsqrtf(var + LN_EPS);
    }
    __syncthreads();
    const int l = tid & 63;
    const int jo = tid >> 6;
    for (int it = 0; it < 8; ++it) {
        int j = it * 4 + jo;
        int w = w0 + j;
        size_t token = ((size_t)(b * NWH + (h >> 3)) * NWH + (w >> 3)) * TOK
                       + ((h & 7) * 8 + (w & 7));
        float mu = Mu[j], rs = Rsig[j];
#pragma unroll
        for (int rep = 0; rep < 3; ++rep) {
            int c = l + rep * 64;
            pb[token * PBP + c] = f2bf((T[c][j] - mu) * rs * ln_g[c] + ln_b[c]);
        }
    }
}

// ---------------------------------------------------------------------------
// K456: MEGA kernel — attention + gMLP + proj + recon, 1 window (64 tokens)
// per block, 4 waves. Round-10 change: weight chunks halved to 12 KB so the
// LDS union shrinks (Blob 33792 -> 24064 B) -> total 50688 B -> 3 blocks/CU.
// Chunking: W1 sub = 32 hidden rows x 192 k; W2 sub = 96 n-rows x 64 k;
// Wp/Wr = 32 n-rows x 192 k. All linear slices of existing prepped layouts;
// accumulator index maps (i <-> n = i*16+l16) identical to round 9.
__launch_bounds__(256, 3)
__global__ void mega_kernel(const ushort* __restrict__ pb,
                            const ushort* __restrict__ WqkvT,
                            const float* __restrict__ b_qkv,
                            const ushort* __restrict__ W1T,
                            const float* __restrict__ b_g1,
                            const ushort* __restrict__ W2C,
                            const float* __restrict__ b_g2,
                            const ushort* __restrict__ WpT,
                            const float* __restrict__ b_proj,
                            const ushort* __restrict__ WrT,
                            const float* __restrict__ b_rec,
                            float* __restrict__ Fout,
                            float* __restrict__ loss) {
    __shared__ __align__(16) ushort Ab[64 * PBP];   // 25600 B: pb -> V -> prod -> F
    __shared__ __align__(16) ushort Blob[12032];    // 24064 B union region
    __shared__ float red[256];
    // attn-phase aliases (24064 B of Blob)
    ushort* Qb  = Blob;                 // 64*40 = 2560
    ushort* Kb  = Blob + 2560;          // 64*40 = 2560
    ushort* Vt  = Blob + 5120;          // 32*72 = 2304
    ushort* Pbf = Blob + 7424;          // 64*72 = 4608
    // gmlp/proj-phase aliases
    ushort* Wb  = Blob;                 // 6144 ushorts = 12288 B chunk
    ushort* Hb  = Blob + 6144;          // 64*72 = 4608 ushorts

    const int tid = threadIdx.x;
    const int lane = tid & 63, wave = tid >> 6;
    const int quad = lane >> 4, l16 = lane & 15;
    const int m0 = wave * 16;
    const int sw = (l16 & 7) << 3;      // read-side XOR swizzle (ushort units)
    const size_t tok0 = (size_t)blockIdx.x * 64;

    // 12KB-chunk staging offsets: 3 x 16B per thread.
    int srcA3[3], srcB3[3], dst3[3];
#pragma unroll
    for (int c = 0; c < 3; ++c) {
        int P = (wave * 3 + c) * 1024 + lane * 16;
        dst3[c] = (wave * 3 + c) * 1024;            // wave-uniform LDS base
        int rA = P / 384;                           // A-type: 384B rows
        int mA = P - rA * 384;
        srcA3[c] = rA * 384 + (mA ^ ((rA & 7) << 4));
        srcB3[c] = P ^ (((P >> 7) & 7) << 4);       // B-type: 128B rows
    }
    char* WbB = (char*)Wb;
    char* AbB = (char*)Ab;

#define ISSUE_W3(SRC, OFFS)                                                   \
    _Pragma("unroll")                                                         \
    for (int c = 0; c < 3; ++c)                                               \
        gload16(WbB + dst3[c], (const char*)(SRC) + OFFS[c]);
// 2 N-tiles x K=192 from Ab vs 32-row Wb chunk (384B rows, swizzled)
#define G1_TILES(ACC, BASEI)                                                  \
    _Pragma("unroll")                                                         \
    for (int kk = 0; kk < 6; ++kk) {                                          \
        bfrag a = *(const bfrag*)&Ab[(m0 + l16) * PBP + kk * 32 + quad * 8];  \
        _Pragma("unroll")                                                     \
        for (int t = 0; t < 2; ++t) {                                         \
            bfrag b = *(const bfrag*)&Wb[(t * 16 + l16) * 192                 \
                                         + ((kk * 32 + quad * 8) ^ sw)];      \
            ACC[(BASEI) + t] = __builtin_amdgcn_mfma_f32_16x16x32_bf16(       \
                a, b, ACC[(BASEI) + t], 0, 0, 0);                             \
        }                                                                     \
    }
// GEMM2 half S: 6 N-tiles x K=64 from Hb vs 96-row Wb chunk (128B rows)
#define G2_HALF(S)                                                            \
    _Pragma("unroll")                                                         \
    for (int kk = 0; kk < 2; ++kk) {                                          \
        bfrag a = *(const bfrag*)&Hb[(m0 + l16) * 72 + kk * 32 + quad * 8];   \
        _Pragma("unroll")                                                     \
        for (int t = 0; t < 6; ++t) {                                         \
            bfrag b = *(const bfrag*)&Wb[(t * 16 + l16) * 64                  \
                                         + ((kk * 32 + quad * 8) ^ sw)];      \
            acc2[(S) * 6 + t] = __builtin_amdgcn_mfma_f32_16x16x32_bf16(      \
                a, b, acc2[(S) * 6 + t], 0, 0, 0);                            \
        }                                                                     \
    }

    // ---- stage pb tile into Ab (linear gload, pitch PBP) ----
    {
        const char* src = (const char*)(pb + tok0 * PBP);
#pragma unroll
        for (int c = 0; c < 6; ++c) {
            int base = (wave * 6 + c) * 1024;
            gload16(AbB + base, src + base + lane * 16);
        }
        if (wave == 0) gload16(AbB + 24576, src + 24576 + lane * 16);
    }
    __syncthreads();

    // =========================== ATTENTION PHASE ===========================
    f32x4 oacc[12];
#pragma unroll
    for (int i = 0; i < 12; ++i) oacc[i] = (f32x4){0.f, 0.f, 0.f, 0.f};
    unsigned int vpk[12][2];            // packed bf16 V fragments (24 VGPR)

#pragma unroll
    for (int h = 0; h < HEADS; ++h) {
        const ushort* baseQ = WqkvT + (size_t)(h * 32) * 192;
        const ushort* baseK = WqkvT + (size_t)(192 + h * 32) * 192;
        const ushort* baseV = WqkvT + (size_t)(384 + h * 32) * 192;
        f32x4 acc[6];
#pragma unroll
        for (int t = 0; t < 6; ++t) acc[t] = (f32x4){0.f, 0.f, 0.f, 0.f};
#pragma unroll
        for (int kk = 0; kk < 6; ++kk) {
            const int ko = kk * 32 + quad * 8;
            bfrag b0 = *(const bfrag*)&baseQ[(size_t)l16 * 192 + ko];
            bfrag b1 = *(const bfrag*)&baseQ[(size_t)(16 + l16) * 192 + ko];
            bfrag b2 = *(const bfrag*)&baseK[(size_t)l16 * 192 + ko];
            bfrag b3 = *(const bfrag*)&baseK[(size_t)(16 + l16) * 192 + ko];
            bfrag b4 = *(const bfrag*)&baseV[(size_t)l16 * 192 + ko];
            bfrag b5 = *(const bfrag*)&baseV[(size_t)(16 + l16) * 192 + ko];
            bfrag a  = *(const bfrag*)&Ab[(m0 + l16) * PBP + ko];
            __builtin_amdgcn_s_setprio(1);
            acc[0] = __builtin_amdgcn_mfma_f32_16x16x32_bf16(a, b0, acc[0], 0, 0, 0);
            acc[1] = __builtin_amdgcn_mfma_f32_16x16x32_bf16(a, b1, acc[1], 0, 0, 0);
            acc[2] = __builtin_amdgcn_mfma_f32_16x16x32_bf16(a, b2, acc[2], 0, 0, 0);
            acc[3] = __builtin_amdgcn_mfma_f32_16x16x32_bf16(a, b3, acc[3], 0, 0, 0);
            acc[4] = __builtin_amdgcn_mfma_f32_16x16x32_bf16(a, b4, acc[4], 0, 0, 0);
            acc[5] = __builtin_amdgcn_mfma_f32_16x16x32_bf16(a, b5, acc[5], 0, 0, 0);
            __builtin_amdgcn_s_setprio(0);
        }
        // write Q (scale folded), K, V^T to LDS; save V bf16 into vpk regs
#pragma unroll
        for (int t = 0; t < 2; ++t) {
            float bq = b_qkv[h * 32 + t * 16 + l16];
            float bk = b_qkv[192 + h * 32 + t * 16 + l16];
            float bv = b_qkv[384 + h * 32 + t * 16 + l16];
            ushort vb[4];
#pragma unroll
            for (int reg = 0; reg < 4; ++reg) {
                int row = m0 + quad * 4 + reg;
                Qb[row * 40 + t * 16 + l16] = f2bf((acc[t][reg] + bq) * ATTN_SCALE);
                Kb[row * 40 + t * 16 + l16] = f2bf(acc[t + 2][reg] + bk);
                ushort vv = f2bf(acc[t + 4][reg] + bv);
                Vt[(t * 16 + l16) * 72 + row] = vv;
                vb[reg] = vv;
            }
            vpk[h * 2 + t][0] = (unsigned int)vb[0] | ((unsigned int)vb[1] << 16);
            vpk[h * 2 + t][1] = (unsigned int)vb[2] | ((unsigned int)vb[3] << 16);
        }
        __syncthreads();

        // ---- S = Q.K^T ----
        f32x4 s[4];
        {
            bfrag aq = *(const bfrag*)&Qb[(m0 + l16) * 40 + quad * 8];
            bfrag k0 = *(const bfrag*)&Kb[(l16) * 40 + quad * 8];
            bfrag k1 = *(const bfrag*)&Kb[(16 + l16) * 40 + quad * 8];
            bfrag k2 = *(const bfrag*)&Kb[(32 + l16) * 40 + quad * 8];
            bfrag k3 = *(const bfrag*)&Kb[(48 + l16) * 40 + quad * 8];
            __builtin_amdgcn_s_setprio(1);
            s[0] = __builtin_amdgcn_mfma_f32_16x16x32_bf16(
                aq, k0, (f32x4){0.f, 0.f, 0.f, 0.f}, 0, 0, 0);
            s[1] = __builtin_amdgcn_mfma_f32_16x16x32_bf16(
                aq, k1, (f32x4){0.f, 0.f, 0.f, 0.f}, 0, 0, 0);
            s[2] = __builtin_amdgcn_mfma_f32_16x16x32_bf16(
                aq, k2, (f32x4){0.f, 0.f, 0.f, 0.f}, 0, 0, 0);
            s[3] = __builtin_amdgcn_mfma_f32_16x16x32_bf16(
                aq, k3, (f32x4){0.f, 0.f, 0.f, 0.f}, 0, 0, 0);
            __builtin_amdgcn_s_setprio(0);
        }
        // ---- softmax per row ----
#pragma unroll
        for (int reg = 0; reg < 4; ++reg) {
            float mx = fmaxf(fmaxf(s[0][reg], s[1][reg]), fmaxf(s[2][reg], s[3][reg]));
            mx = fmaxf(mx, __shfl_xor(mx, 1));
            mx = fmaxf(mx, __shfl_xor(mx, 2));
            mx = fmaxf(mx, __shfl_xor(mx, 4));
            mx = fmaxf(mx, __shfl_xor(mx, 8));
            float e[4], sum = 0.f;
#pragma unroll
            for (int t = 0; t < 4; ++t) { e[t] = __expf(s[t][reg] - mx); sum += e[t]; }
            sum += __shfl_xor(sum, 1);
            sum += __shfl_xor(sum, 2);
            sum += __shfl_xor(sum, 4);
            sum += __shfl_xor(sum, 8);
            float inv = 1.0f / sum;
            int row = m0 + quad * 4 + reg;
#pragma unroll
            for (int t = 0; t < 4; ++t)
                Pbf[row * 72 + t * 16 + l16] = f2bf(e[t] * inv);
        }
        __syncthreads();

        // ---- O = P.V -> oacc[h*2 + t] ----
#pragma unroll
        for (int kk = 0; kk < 2; ++kk) {
            bfrag a  = *(const bfrag*)&Pbf[(m0 + l16) * 72 + kk * 32 + quad * 8];
            bfrag v0 = *(const bfrag*)&Vt[(l16) * 72 + kk * 32 + quad * 8];
            bfrag v1 = *(const bfrag*)&Vt[(16 + l16) * 72 + kk * 32 + quad * 8];
            __builtin_amdgcn_s_setprio(1);
            oacc[h * 2 + 0] = __builtin_amdgcn_mfma_f32_16x16x32_bf16(
                a, v0, oacc[h * 2 + 0], 0, 0, 0);
            oacc[h * 2 + 1] = __builtin_amdgcn_mfma_f32_16x16x32_bf16(
                a, v1, oacc[h * 2 + 1], 0, 0, 0);
            __builtin_amdgcn_s_setprio(0);
        }
        __syncthreads();   // protect Qb/Kb/Vt/Pbf before next head's writes
    }

    // ========================== GMLP PHASE =================================
    // write V (bf16, from vpk) into own-wave rows of Ab — pb is dead.
#pragma unroll
    for (int i = 0; i < 12; ++i) {
        int n = i * 16 + l16;
        Ab[(m0 + quad * 4 + 0) * PBP + n] = (ushort)(vpk[i][0] & 0xFFFF);
        Ab[(m0 + quad * 4 + 1) * PBP + n] = (ushort)(vpk[i][0] >> 16);
        Ab[(m0 + quad * 4 + 2) * PBP + n] = (ushort)(vpk[i][1] & 0xFFFF);
        Ab[(m0 + quad * 4 + 3) * PBP + n] = (ushort)(vpk[i][1] >> 16);
    }
    ISSUE_W3(W1T, srcA3);               // W1(0, sub 0); Wb overwrites attn bufs
    __syncthreads();                    // ready; V writes drained

    f32x4 acc2[12];
#pragma unroll
    for (int i = 0; i < 12; ++i) acc2[i] = (f32x4){0.f, 0.f, 0.f, 0.f};
    for (int hc = 0; hc < 12; ++hc) {
        f32x4 acc1[4];
#pragma unroll
        for (int t = 0; t < 4; ++t) acc1[t] = (f32x4){0.f, 0.f, 0.f, 0.f};
        G1_TILES(acc1, 0);                    // W1(hc,0): hidden cols 0..31
        __syncthreads();
        ISSUE_W3((const char*)W1T + (size_t)hc * 24576 + 12288, srcA3);
        __syncthreads();
        G1_TILES(acc1, 2);                    // W1(hc,1): hidden cols 32..63
        // gelu -> Hb (own-wave rows); Hb region disjoint from Wb
#pragma unroll
        for (int t = 0; t < 4; ++t) {
            int n = t * 16 + l16;
            float bb = b_g1[hc * 64 + n];
#pragma unroll
            for (int reg = 0; reg < 4; ++reg) {
                float xv = acc1[t][reg] + bb;
                Hb[(m0 + quad * 4 + reg) * 72 + n] = f2bf(gelu_erf(xv));
            }
        }
        __syncthreads();                  // W1b reads + Hb writes done
        ISSUE_W3((const char*)W2C + (size_t)hc * 24576, srcB3);
        __syncthreads();                  // W2(hc,0) ready (n-rows 0..95)
        G2_HALF(0);
        __syncthreads();
        ISSUE_W3((const char*)W2C + (size_t)hc * 24576 + 12288, srcB3);
        __syncthreads();                  // W2(hc,1) ready (n-rows 96..191)
        G2_HALF(1);
        if (hc < 11) {
            __syncthreads();              // W2b reads done
            ISSUE_W3((const char*)W1T + (size_t)(hc + 1) * 24576, srcA3);
            __syncthreads();              // W1(hc+1,0) ready
        }
    }
    // product = oacc * (g + b_g2) -> bf16 into own-wave rows of Ab (V dead)
#pragma unroll
    for (int t = 0; t < 12; ++t) {
        int c = t * 16 + l16;
        float bg = b_g2[c];
#pragma unroll
        for (int reg = 0; reg < 4; ++reg) {
            int r = m0 + quad * 4 + reg;
            Ab[r * PBP + c] = f2bf(oacc[t][reg] * (acc2[t][reg] + bg));
        }
    }
    __syncthreads();                      // W2 reads done before Wb overwrite
    ISSUE_W3(WpT, srcA3);                 // Wp chunk 0 (n-rows 0..31)
    __syncthreads();                      // ready; product drained

    // ========================== PROJ / RECON PHASE =========================
    f32x4 facc[12];
#pragma unroll
    for (int i = 0; i < 12; ++i) facc[i] = (f32x4){0.f, 0.f, 0.f, 0.f};
#pragma unroll
    for (int c = 0; c < 6; ++c) {
        G1_TILES(facc, c * 2);            // Wp(c): n-rows c*32..c*32+31
        if (c < 5) {
            __syncthreads();
            ISSUE_W3((const char*)WpT + (size_t)(c + 1) * 12288, srcA3);
            __syncthreads();
        }
    }
    // write F: fp32 to Fout (for K8), bf16 into own-wave rows of Ab (recon A)
#pragma unroll
    for (int i = 0; i < 12; ++i) {
        int n = i * 16 + l16;
        float bp = b_proj[n];
#pragma unroll
        for (int reg = 0; reg < 4; ++reg) {
            int r = m0 + quad * 4 + reg;
            float fv = facc[i][reg] + bp;
            Fout[(tok0 + r) * (size_t)CDIM + n] = fv;
            Ab[r * PBP + n] = f2bf(fv);
        }
    }
    __syncthreads();                      // Wp(5) reads done
    ISSUE_W3(WrT, srcA3);
    __syncthreads();                      // Wr(0) ready

    f32x4 racc[12];
#pragma unroll
    for (int i = 0; i < 12; ++i) racc[i] = (f32x4){0.f, 0.f, 0.f, 0.f};
#pragma unroll
    for (int c = 0; c < 6; ++c) {
        G1_TILES(racc, c * 2);            // Wr(c): n-rows c*32..c*32+31
        if (c < 5) {
            __syncthreads();
            ISSUE_W3((const char*)WrT + (size_t)(c + 1) * 12288, srcA3);
            __syncthreads();
        }
    }

    // ---- L1 loss vs pb ----
    float ls = 0.f;
#pragma unroll
    for (int i = 0; i < 12; ++i) {
        int n = i * 16 + l16;
        float br = b_rec[n];
#pragma unroll
        for (int reg = 0; reg < 4; ++reg) {
            int r = m0 + quad * 4 + reg;
            float rv = racc[i][reg] + br;
            ls += fabsf(rv - bf2f(pb[(tok0 + r) * PBP + n]));
        }
    }
    red[tid] = ls;
    __syncthreads();
    for (int s = 128; s > 0; s >>= 1) {
        if (tid < s) red[tid] += red[tid + s];
        __syncthreads();
    }
    if (tid == 0) atomicAdd(loss, red[0] * (0.1f / (float)IMGSZ));
#undef ISSUE_W3
#undef G1_TILES
#undef G2_HALF
}

// ---------------------------------------------------------------------------
// K8: window reverse + residual.
__launch_bounds__(256)
__global__ void reverse_res_kernel(const float* __restrict__ fused,
                                   const float* __restrict__ x,
                                   float* __restrict__ out) {
    __shared__ float T[CDIM][33];
    const int tid = threadIdx.x;
    const int wt = blockIdx.x, h = blockIdx.y, b = blockIdx.z;
    const int w0 = wt * 32;
    const int l = tid & 63, jo = tid >> 6;
    for (int it = 0; it < 8; ++it) {
        int j = it * 4 + jo;
        int w = w0 + j;
        size_t token = ((size_t)(b * NWH + (h >> 3)) * NWH + (w >> 3)) * TOK
                       + ((h & 7) * 8 + (w & 7));
#pragma unroll
        for (int rep = 0; rep < 3; ++rep) {
            int c = l + rep * 64;
            T[c][j] = fused[token * CDIM + c];
        }
    }
    __syncthreads();
    const size_t rowbase = (size_t)b * CDIM * HWSZ + (size_t)h * WDIM + w0;
    for (int idx = tid; idx < CDIM * 32; idx += 256) {
        int c = idx >> 5, j = idx & 31;
        size_t gp = rowbase + (size_t)c * HWSZ + j;
        out[gp] = T[c][j] + x[gp];
    }
}

// ---------------------------------------------------------------------------
extern "C" void kernel_launch(void* const* d_in, const int* in_sizes, int n_in,
                              void* d_out, int out_size, void* d_ws, size_t ws_size,
                              hipStream_t stream) {
    const float* x      = (const float*)d_in[0];
    const float* w_pre1 = (const float*)d_in[1];
    const float* b_pre1 = (const float*)d_in[2];
    const float* w_dw   = (const float*)d_in[3];
    const float* b_dw   = (const float*)d_in[4];
    const float* ln_g   = (const float*)d_in[5];
    const float* ln_b   = (const float*)d_in[6];
    const float* w_qkv  = (const float*)d_in[7];
    const float* b_qkv  = (const float*)d_in[8];
    const float* w_proj = (const float*)d_in[9];
    const float* b_proj = (const float*)d_in[10];
    const float* w_g1   = (const float*)d_in[11];
    const float* b_g1   = (const float*)d_in[12];
    const float* w_g2   = (const float*)d_in[13];
    const float* b_g2   = (const float*)d_in[14];
    const float* w_rec  = (const float*)d_in[15];
    const float* b_rec  = (const float*)d_in[16];

    float* OutR = (float*)d_out;
    float* loss = OutR + (size_t)IMGSZ;
    float* A    = (float*)d_ws;            // 154 MB fp32 region

    // d_out layout during pipeline (front->back):
    //  [f1 fp32 full]  ->  [pb bf16 (pitch 200) ~80MB | bf16 weights ~1MB]
    //  final: out fp32 full + loss scalar
    // d_ws: f2 (154MB) -> F (fused, 154MB)
    ushort* pb    = (ushort*)d_out;                    // MTOK*PBP bf16
    ushort* WqkvT = pb    + (size_t)MTOK * PBP;        // 576x192 (n-major, k-contig)
    ushort* W1T   = WqkvT + 576 * 192;                 // 768x192
    ushort* W2C   = W1T   + 768 * 192;                 // [12][192][64] chunk-contig
    ushort* WpT   = W2C   + 192 * 768;                 // 192x192
    ushort* WrT   = WpT   + 192 * 192;                 // 192x192

    hipMemsetAsync(loss, 0, sizeof(float), stream);

    // K1: f1 = conv1x1(x) -> d_out (fp32)
    conv1x1_kernel<<<dim3(HWSZ / 64, CDIM / 64, BATCH), 256, 0, stream>>>(
        x, w_pre1, b_pre1, OutR);
    // K2: f2 = dwconv(f1) -> A
    dwconv_kernel<<<IMGSZ / 256, 256, 0, stream>>>(OutR, w_dw, b_dw, A);
    // prep bf16 weights (after f1 is dead)
    prep_weights_kernel<<<(768 * 192 + 255) / 256, 256, 0, stream>>>(
        w_qkv, w_g1, w_g2, w_proj, w_rec, WqkvT, W1T, W2C, WpT, WrT);
    // K3: pb = LN+partition(f2) -> d_out front (bf16, pitch PBP)
    ln_part_kernel<<<dim3(WDIM / 32, HDIM, BATCH), 256, 0, stream>>>(
        A, ln_g, ln_b, pb);
    // K456: attention + gmlp + proj + recon fused -> F in A (f2 dead)
    mega_kernel<<<NWIN, 256, 0, stream>>>(
        pb, WqkvT, b_qkv, W1T, b_g1, W2C, b_g2, WpT, b_proj, WrT, b_rec,
        A, loss);
    // K8: out = reverse(F) + x -> d_out (pb/weights dead)
    reverse_res_kernel<<<dim3(WDIM / 32, HDIM, BATCH), 256, 0, stream>>>(
        A, x, OutR);
}